// Round 8
// baseline (349.073 us; speedup 1.0000x reference)
//
#include <hip/hip_runtime.h>
#include <hip/hip_bf16.h>
#include <math.h>

// Problem constants (Qwen3-style attention block)
#define B_   2
#define S_   2048
#define D_   2048
#define H_   16
#define HK_  8
#define HD_  128
#define BS_  (B_ * S_)          // 4096 rows
#define NQKV 4096               // combined q(2048) + k(1024) + v(1024) cols
#define SCALE 0.08838834764831845f  // 1/sqrt(128)

typedef __bf16 bf16x8 __attribute__((ext_vector_type(8)));
typedef __bf16 bf16x4 __attribute__((ext_vector_type(4)));
typedef float  f32x4  __attribute__((ext_vector_type(4)));

#define AS1(p) ((const __attribute__((address_space(1))) void*)(p))
#define AS3(p) ((__attribute__((address_space(3))) void*)(p))

// 16-lane (DPP row) rotate-reduce sum: VALU latency, no LDS round-trip.
template <int S>
__device__ __forceinline__ float ror16(float x) {
    return __builtin_bit_cast(float, __builtin_amdgcn_update_dpp(
        0, __builtin_bit_cast(int, x), 0x120 | S, 0xF, 0xF, true));
}
__device__ __forceinline__ float row_sum16(float x) {
    x += ror16<8>(x);
    x += ror16<4>(x);
    x += ror16<2>(x);
    x += ror16<1>(x);
    return x;
}

// ---------------------------------------------------------------------------
// All fp32 -> bf16 converts in one launch.
// ---------------------------------------------------------------------------
__global__ __launch_bounds__(256) void cvt_all(const float* __restrict__ x,
                                               const float* __restrict__ wq,
                                               const float* __restrict__ wk,
                                               const float* __restrict__ wv,
                                               const float* __restrict__ wo,
                                               __bf16* __restrict__ xb,
                                               __bf16* __restrict__ wb,
                                               __bf16* __restrict__ wob) {
    int bid = blockIdx.x;
    const float* src;
    __bf16* dst;
    int i4;
    if (bid < 8192)       { src = x;  dst = xb;                    i4 = bid * 256; }
    else if (bid < 12288) { src = wq; dst = wb;                    i4 = (bid - 8192) * 256; }
    else if (bid < 14336) { src = wk; dst = wb + (size_t)4194304;  i4 = (bid - 12288) * 256; }
    else if (bid < 16384) { src = wv; dst = wb + (size_t)6291456;  i4 = (bid - 14336) * 256; }
    else                  { src = wo; dst = wob;                   i4 = (bid - 16384) * 256; }
    i4 += threadIdx.x;
    float4 v = reinterpret_cast<const float4*>(src)[i4];
    bf16x4 o = {(__bf16)v.x, (__bf16)v.y, (__bf16)v.z, (__bf16)v.w};
    reinterpret_cast<bf16x4*>(dst)[i4] = o;
}

// ---------------------------------------------------------------------------
// RoPE cos/sin table: tab[s][0..63]=cos(ang_i), tab[s][64..127]=sin(ang_i).
// ---------------------------------------------------------------------------
__global__ __launch_bounds__(128) void build_rope(float* __restrict__ tab) {
    int s = blockIdx.x;
    int d = threadIdx.x;
    int i = d & 63;
    float inv_freq = exp2f(-19.931568569324174f * (float)(2 * i) * (1.0f / 128.0f));
    float ang = (float)s * inv_freq;
    float sn, cs;
    sincosf(ang, &sn, &cs);
    tab[s * 128 + d] = (d < 64) ? cs : sn;
}

// ---------------------------------------------------------------------------
// 256x256 8-phase bf16 MFMA NT GEMM — R4 schedule (best measured: 82-83 µs,
// no spill). One barrier per phase: {ds_read; stg; [vmcnt]; BAR; lgkm0+schedbar;
// MFMA}. b0f/b1f double-buffered B fragments; vmcnt(4) at ph4/ph8 pre-barrier.
// XOR-swizzled LDS (conflict-free, verified), XCD supertile swizzle.
// R5/R6/R7 schedule variants all landed 82-96 µs at MfmaUtil 31-33% — this
// structure's ceiling on this chip; keep the best.
// ---------------------------------------------------------------------------
__global__ __launch_bounds__(512, 2) void gemm_bf16_8ph(const __bf16* __restrict__ A,
                                                        const __bf16* __restrict__ W,
                                                        __bf16* __restrict__ C,
                                                        int M, int N, int K) {
    __shared__ __bf16 lds[2][2][256 * 64];   // [buf][A=0/B=1][row*64 + chunk]

    const int t    = threadIdx.x;            // 0..511
    const int w    = t >> 6;                 // wave 0..7
    const int lane = t & 63;
    const int col  = lane & 15;
    const int quad = lane >> 4;
    const int c7   = col & 7;
    const int wm   = w >> 2;                 // 0..1  (2 M-warps, 128 rows each)
    const int wn   = w & 3;                  // 0..3  (4 N-warps, 64 cols each)

    // XCD-aware supertile swizzle (16x16 block grid, 8 XCDs, 256%8==0).
    const int bid = blockIdx.x;
    const int nid = (bid & 7) * 32 + (bid >> 3);
    const int st  = nid >> 4;
    const int wi  = nid & 15;
    const int m0 = ((st >> 2) * 4 + (wi >> 2)) * 256;
    const int n0 = ((st & 3) * 4 + (wi & 3)) * 256;

    // staging source (per-lane): wave w covers rows w*16..w*16+15 of a half
    const int lr8 = lane >> 3;                       // 0..7
    const int sw8 = ((lane & 7) ^ lr8) * 8;          // swizzled K-chunk (elems)
    const __bf16* Ag = A + (size_t)(m0 + w * 16 + lr8) * K + sw8;
    const __bf16* Wg = W + (size_t)(n0 + w * 16 + lr8) * K + sw8;

    const int nkt = K >> 6;      // number of 64-wide K-tiles (32 for K=2048)
    const int nit = nkt >> 1;    // main-loop iterations (2 K-tiles each)

    // fragment read bases (element offsets within a [256][64] panel)
    const int aBase = (wm * 128 + col) * 64;
    const int bBase = (wn * 64 + col) * 64;
    const int kx0 = (quad ^ c7) * 8;                 // kk=0 chunk offset
    const int kx1 = ((4 + quad) ^ c7) * 8;           // kk=1

    f32x4 acc[8][4];
    #pragma unroll
    for (int i = 0; i < 8; i++)
        #pragma unroll
        for (int j = 0; j < 4; j++) acc[i][j] = (f32x4){0.f, 0.f, 0.f, 0.f};

    bf16x8 a[4][2], a2[4][2], b0f[2][2], b1f[2][2];

    auto stg = [&](int ktv, int bufc, int ab, int half) {
        if (ktv >= nkt) return;
        const __bf16* gb = (ab ? Wg : Ag) + (size_t)half * 128 * K + (size_t)ktv * 64;
        __bf16* db = &lds[bufc][ab][(half * 128 + w * 16) * 64];
        __builtin_amdgcn_global_load_lds(AS1(gb), AS3(db), 16, 0, 0);
        __builtin_amdgcn_global_load_lds(AS1(gb + (size_t)8 * K), AS3(db + 512), 16, 0, 0);
    };
    auto lda = [&](bf16x8 (&dst)[4][2], const __bf16* panel, int g) {
        #pragma unroll
        for (int mi = 0; mi < 4; mi++) {
            dst[mi][0] = *reinterpret_cast<const bf16x8*>(&panel[aBase + (g * 64 + mi * 16) * 64 + kx0]);
            dst[mi][1] = *reinterpret_cast<const bf16x8*>(&panel[aBase + (g * 64 + mi * 16) * 64 + kx1]);
        }
    };
    auto ldb = [&](bf16x8 (&dst)[2][2], const __bf16* panel, int ng) {
        #pragma unroll
        for (int ni = 0; ni < 2; ni++) {
            dst[ni][0] = *reinterpret_cast<const bf16x8*>(&panel[bBase + (ng * 32 + ni * 16) * 64 + kx0]);
            dst[ni][1] = *reinterpret_cast<const bf16x8*>(&panel[bBase + (ng * 32 + ni * 16) * 64 + kx1]);
        }
    };
    auto mm = [&](bf16x8 (&af)[4][2], bf16x8 (&bfr)[2][2], int g, int ng) {
        __builtin_amdgcn_s_setprio(1);
        #pragma unroll
        for (int mi = 0; mi < 4; mi++)
            #pragma unroll
            for (int ni = 0; ni < 2; ni++) {
                f32x4 c = acc[g * 4 + mi][ng * 2 + ni];
                c = __builtin_amdgcn_mfma_f32_16x16x32_bf16(af[mi][0], bfr[ni][0], c, 0, 0, 0);
                c = __builtin_amdgcn_mfma_f32_16x16x32_bf16(af[mi][1], bfr[ni][1], c, 0, 0, 0);
                acc[g * 4 + mi][ng * 2 + ni] = c;
            }
        __builtin_amdgcn_s_setprio(0);
    };

#define BAR  __builtin_amdgcn_s_barrier()
#define LGKM0 do { asm volatile("s_waitcnt lgkmcnt(0)" ::: "memory"); \
                   __builtin_amdgcn_sched_barrier(0); } while (0)
#define VM(n) asm volatile("s_waitcnt vmcnt(" #n ")" ::: "memory")

    // ---- prologue: kt0 {A0,A1,B0,B1}, kt1 {A0,A1}; land kt0, keep 2 in flight
    stg(0, 0, 0, 0); stg(0, 0, 0, 1); stg(0, 0, 1, 0); stg(0, 0, 1, 1);
    stg(1, 1, 0, 0); stg(1, 1, 0, 1);
    VM(4);
    BAR;

    #pragma unroll 1
    for (int it = 0; it < nit; ++it) {
        const int k2 = it * 2;
        const bool last = (it == nit - 1);

        const __bf16* A0p = &lds[0][0][0];
        const __bf16* B0p = &lds[0][1][0];
        const __bf16* A1p = &lds[1][0][0];
        const __bf16* B1p = &lds[1][1][0];

        // ---- K-tile k2 (buf0): phases 1-4
        lda(a, A0p, 0); ldb(b0f, B0p, 0);
        stg(k2 + 1, 1, 1, 0);
        BAR; LGKM0;
        mm(a, b0f, 0, 0);
        lda(a2, A0p, 1);
        stg(k2 + 1, 1, 1, 1);
        BAR; LGKM0;
        mm(a2, b0f, 1, 0);
        ldb(b1f, B0p, 1);
        stg(k2 + 2, 0, 0, 0);
        BAR; LGKM0;
        mm(a, b1f, 0, 1);
        stg(k2 + 2, 0, 0, 1);
        if (last) VM(0); else VM(4);
        BAR;
        mm(a2, b1f, 1, 1);

        // ---- K-tile k2+1 (buf1): phases 5-8
        lda(a, A1p, 0); ldb(b0f, B1p, 0);
        stg(k2 + 2, 0, 1, 0);
        BAR; LGKM0;
        mm(a, b0f, 0, 0);
        lda(a2, A1p, 1);
        stg(k2 + 2, 0, 1, 1);
        BAR; LGKM0;
        mm(a2, b0f, 1, 0);
        ldb(b1f, B1p, 1);
        stg(k2 + 3, 1, 0, 0);
        BAR; LGKM0;
        mm(a, b1f, 0, 1);
        stg(k2 + 3, 1, 0, 1);
        if (!last) { VM(4); }
        BAR;
        mm(a2, b1f, 1, 1);
    }

#undef BAR
#undef LGKM0
#undef VM

    // ---- epilogue: C write (verified C/D mapping)
    #pragma unroll
    for (int m8 = 0; m8 < 8; m8++) {
        #pragma unroll
        for (int r = 0; r < 4; r++) {
            size_t row = m0 + wm * 128 + m8 * 16 + quad * 4 + r;
            __bf16* cp = C + row * N + n0 + wn * 64 + col;
            #pragma unroll
            for (int n4 = 0; n4 < 4; n4++) cp[n4 * 16] = (__bf16)acc[m8][n4][r];
        }
    }
}

// ---------------------------------------------------------------------------
// bf16 MFMA NT GEMM, 128(M)x64(N) tile: for narrow-N GEMMs where a large
// tile would leave CUs idle (out-proj: N=2048 -> 1024 blocks).
// ---------------------------------------------------------------------------
template <typename CT>
__global__ __launch_bounds__(256) void gemm_bf16_nt_n64(const __bf16* __restrict__ A,
                                                        const __bf16* __restrict__ W,
                                                        CT* __restrict__ C,
                                                        int M, int N, int K) {
    __shared__ __bf16 As[128 * 64];
    __shared__ __bf16 Bs[64 * 64];

    const int t    = threadIdx.x;
    const int w    = t >> 6;
    const int lane = t & 63;
    const int col  = lane & 15;
    const int quad = lane >> 4;
    const int wm   = w >> 1;      // 0..1 -> M half (64 rows)
    const int wn   = w & 1;       // 0..1 -> N half (32 cols)

    const int m0 = blockIdx.x * 128;
    const int n0 = blockIdx.y * 64;

    const int lrow8 = lane >> 3;
    const int lch   = ((lane & 7) ^ lrow8) * 8;

    const __bf16* agp = A + (size_t)(m0 + w * 32 + lrow8) * K + lch;
    const __bf16* wgp = W + (size_t)(n0 + w * 16 + lrow8) * K + lch;
    __bf16* alp = As + (w * 32) * 64;
    __bf16* blp = Bs + (w * 16) * 64;

    const int c7 = col & 7;

    f32x4 acc[4][2];
    #pragma unroll
    for (int m = 0; m < 4; m++)
        #pragma unroll
        for (int n = 0; n < 2; n++) acc[m][n] = (f32x4){0.f, 0.f, 0.f, 0.f};

    #pragma unroll 1
    for (int k0 = 0; k0 < K; k0 += 64) {
        #pragma unroll
        for (int j = 0; j < 4; j++)
            __builtin_amdgcn_global_load_lds(AS1(agp + k0 + (size_t)(j * 8) * K),
                                             AS3(alp + j * 512), 16, 0, 0);
        #pragma unroll
        for (int j = 0; j < 2; j++)
            __builtin_amdgcn_global_load_lds(AS1(wgp + k0 + (size_t)(j * 8) * K),
                                             AS3(blp + j * 512), 16, 0, 0);
        __syncthreads();

        #pragma unroll
        for (int kk = 0; kk < 2; kk++) {
            bf16x8 af[4], bfr[2];
            #pragma unroll
            for (int m = 0; m < 4; m++)
                af[m] = *reinterpret_cast<const bf16x8*>(
                    &As[(wm * 64 + m * 16 + col) * 64 + ((kk * 4 + quad) ^ c7) * 8]);
            #pragma unroll
            for (int n = 0; n < 2; n++)
                bfr[n] = *reinterpret_cast<const bf16x8*>(
                    &Bs[(wn * 32 + n * 16 + col) * 64 + ((kk * 4 + quad) ^ c7) * 8]);

            #pragma unroll
            for (int m = 0; m < 4; m++)
                #pragma unroll
                for (int n = 0; n < 2; n++)
                    acc[m][n] = __builtin_amdgcn_mfma_f32_16x16x32_bf16(af[m], bfr[n], acc[m][n], 0, 0, 0);
        }
        __syncthreads();
    }

    #pragma unroll
    for (int m = 0; m < 4; m++) {
        #pragma unroll
        for (int r = 0; r < 4; r++) {
            size_t row = m0 + wm * 64 + m * 16 + quad * 4 + r;
            CT* cp = C + row * N + n0 + wn * 32 + col;
            #pragma unroll
            for (int n = 0; n < 2; n++) cp[n * 16] = (CT)acc[m][n][r];
        }
    }
}

// ---------------------------------------------------------------------------
// Fused per-head RMSNorm + RoPE, vectorized: one head per 16-lane DPP row.
// ---------------------------------------------------------------------------
__global__ __launch_bounds__(256) void norm_rope(__bf16* __restrict__ qkv,
                                                 const float* __restrict__ qw,
                                                 const float* __restrict__ kw,
                                                 const float* __restrict__ tab) {
    const int g    = blockIdx.x * 16 + (threadIdx.x >> 4);  // head-instance
    const int l    = threadIdx.x & 15;
    const int row  = g / 24;
    const int head = g - row * 24;
    const int s    = row & (S_ - 1);

    const float* w = (head < H_) ? qw : kw;
    __bf16* p = qkv + (size_t)row * NQKV + head * HD_ + l * 8;

    bf16x8 xv = *reinterpret_cast<const bf16x8*>(p);
    float xf[8];
    float ss = 0.f;
    #pragma unroll
    for (int j = 0; j < 8; j++) { xf[j] = (float)xv[j]; ss = fmaf(xf[j], xf[j], ss); }
    ss = row_sum16(ss);
    float rs = rsqrtf(ss * (1.0f / 128.0f) + 1e-6f);

    // normed value (fp32)
    float nf[8];
    const float4 w0 = *reinterpret_cast<const float4*>(&w[l * 8]);
    const float4 w1 = *reinterpret_cast<const float4*>(&w[l * 8 + 4]);
    nf[0] = xf[0] * rs * w0.x; nf[1] = xf[1] * rs * w0.y;
    nf[2] = xf[2] * rs * w0.z; nf[3] = xf[3] * rs * w0.w;
    nf[4] = xf[4] * rs * w1.x; nf[5] = xf[5] * rs * w1.y;
    nf[6] = xf[6] * rs * w1.z; nf[7] = xf[7] * rs * w1.w;

    // RoPE pair values from the other half (lane l^8, same j)
    float of[8];
    #pragma unroll
    for (int j = 0; j < 8; j++) of[j] = __shfl_xor(nf[j], 8);

    // cos/sin for freq index i = (l&7)*8 + j
    const int ib = (l & 7) * 8;
    const float4 c0 = *reinterpret_cast<const float4*>(&tab[s * 128 + ib]);
    const float4 c1 = *reinterpret_cast<const float4*>(&tab[s * 128 + ib + 4]);
    const float4 s0 = *reinterpret_cast<const float4*>(&tab[s * 128 + 64 + ib]);
    const float4 s1 = *reinterpret_cast<const float4*>(&tab[s * 128 + 64 + ib + 4]);
    float cs[8] = {c0.x, c0.y, c0.z, c0.w, c1.x, c1.y, c1.z, c1.w};
    float sn[8] = {s0.x, s0.y, s0.z, s0.w, s1.x, s1.y, s1.z, s1.w};

    bf16x8 out;
    if (l < 8) {
        #pragma unroll
        for (int j = 0; j < 8; j++) out[j] = (__bf16)(nf[j] * cs[j] - of[j] * sn[j]);
    } else {
        #pragma unroll
        for (int j = 0; j < 8; j++) out[j] = (__bf16)(of[j] * sn[j] + nf[j] * cs[j]);
    }
    *reinterpret_cast<bf16x8*>(p) = out;
}

// ---------------------------------------------------------------------------
// V transpose: vt[(b*HK+kvh)*128 + dim][s] = v[b*S+s][kvh*128+dim]
// ---------------------------------------------------------------------------
__global__ __launch_bounds__(256) void transpose_v(const __bf16* __restrict__ qkv,
                                                   __bf16* __restrict__ vt) {
    __shared__ __bf16 Ls[64][136];
    const int t  = threadIdx.x;
    const int bk = blockIdx.y;            // b*8 + kvh
    const int b  = bk >> 3;
    const int kvh = bk & 7;
    const int s0 = blockIdx.x * 64;

    #pragma unroll
    for (int i = 0; i < 4; i++) {
        int f = t + i * 256;
        int row = f >> 4;
        int d8 = (f & 15) * 8;
        bf16x8 v = *reinterpret_cast<const bf16x8*>(
            &qkv[(size_t)(b * S_ + s0 + row) * NQKV + 3072 + kvh * HD_ + d8]);
        *reinterpret_cast<bf16x8*>(&Ls[row][d8]) = v;
    }
    __syncthreads();

    #pragma unroll
    for (int i = 0; i < 4; i++) {
        int f = t + i * 256;
        int dim = f >> 3;
        int kc = f & 7;
        bf16x8 o;
        #pragma unroll
        for (int e = 0; e < 8; e++) o[e] = Ls[kc * 8 + e][dim];
        *reinterpret_cast<bf16x8*>(
            &vt[((size_t)bk * HD_ + dim) * S_ + s0 + kc * 8]) = o;
    }
}

// ---------------------------------------------------------------------------
// MFMA bf16 flash attention (causal, GQA), fixed-max softmax.
// R8: QBLK 64 -> 128 (2 strips of 16 q-rows per wave). Halves tile-iteration
// count (16896 -> 8704): K/V staging, both barriers, and K/V LDS reads are
// strip-independent (bf/vf reused across strips) so per-work overhead halves
// while MFMA/tile doubles. Q fragments load DIRECTLY from global (no Qs LDS;
// prologue-only, 64B-segment coalesced, L2-hot) so LDS stays 3 blocks/CU:
// Ks 17.4K + Vt 18.4K + Ps[4][32][68] 17.4K = 53.2KB <= 54.6KB.
// Grid: (B*H, S/128) with big q-tiles dispatched first.
// ---------------------------------------------------------------------------
__global__ __launch_bounds__(256) void attn_mfma(const __bf16* __restrict__ qkv,
                                                 const __bf16* __restrict__ vt,
                                                 __bf16* __restrict__ ao) {
    __shared__ __bf16 Ks[64][136];
    __shared__ __bf16 Vt[128][72];
    __shared__ __bf16 Ps[4][32][68];

    const int t    = threadIdx.x;
    const int w    = t >> 6;
    const int lane = t & 63;
    const int col  = lane & 15;
    const int quad = lane >> 4;

    const int bh  = blockIdx.x;
    const int b   = bh >> 4;
    const int h   = bh & 15;
    const int kvh = h >> 1;
    const int qb  = gridDim.y - 1 - blockIdx.y;   // big q-tiles first
    const int r0  = qb * 128;

    const float C0 = SCALE * 1.44269504f;
    const float CM = -12.0f * 1.44269504f;

    const __bf16* vbase = vt + ((size_t)(b * HK_ + kvh) * HD_) * S_;

    // K/V staging slots (per-thread, 4 each)
    const __bf16* kp[4];
    __bf16*       kw_[4];
    const __bf16* vp[4];
    __bf16*       vw_[4];
    #pragma unroll
    for (int i = 0; i < 4; i++) {
        int f = t + i * 256;
        int row = f >> 4, d8 = (f & 15) * 8;
        kp[i]  = qkv + (size_t)(b * S_ + row) * NQKV + 2048 + kvh * HD_ + d8;
        kw_[i] = &Ks[row][d8];
        int dim = f >> 3, kc = f & 7;
        vp[i]  = vbase + (size_t)dim * S_ + kc * 8;
        vw_[i] = &Vt[dim][kc * 8];
    }

    bf16x8 kreg[4], vreg[4];
    #pragma unroll
    for (int i = 0; i < 4; i++) {
        kreg[i] = *reinterpret_cast<const bf16x8*>(kp[i]);  kp[i] += (size_t)64 * NQKV;
        vreg[i] = *reinterpret_cast<const bf16x8*>(vp[i]);  vp[i] += 64;
    }

    // Q fragments direct from global: strip st (0/1), k-chunk k (0..3).
    // q row = r0 + w*32 + st*16 + col; cols h*128 + k*32 + quad*8.
    bf16x8 qf[2][4];
    #pragma unroll
    for (int st = 0; st < 2; st++)
        #pragma unroll
        for (int k = 0; k < 4; k++)
            qf[st][k] = *reinterpret_cast<const bf16x8*>(
                &qkv[(size_t)(b * S_ + r0 + w * 32 + st * 16 + col) * NQKV
                     + h * HD_ + k * 32 + quad * 8]);

    f32x4 o_acc[2][8];
    #pragma unroll
    for (int st = 0; st < 2; st++)
        #pragma unroll
        for (int i = 0; i < 8; i++) o_acc[st][i] = (f32x4){0.f, 0.f, 0.f, 0.f};
    float l_lane[2][4] = {{0.f, 0.f, 0.f, 0.f}, {0.f, 0.f, 0.f, 0.f}};

    const int ntiles = 2 * qb + 2;
    for (int ti = 0; ti < ntiles; ti++) {
        __syncthreads();

        #pragma unroll
        for (int i = 0; i < 4; i++) {
            *reinterpret_cast<bf16x8*>(kw_[i]) = kreg[i];
            *reinterpret_cast<bf16x8*>(vw_[i]) = vreg[i];
        }
        if (ti + 1 < ntiles) {
            #pragma unroll
            for (int i = 0; i < 4; i++) {
                kreg[i] = *reinterpret_cast<const bf16x8*>(kp[i]);  kp[i] += (size_t)64 * NQKV;
                vreg[i] = *reinterpret_cast<const bf16x8*>(vp[i]);  vp[i] += 64;
            }
        }
        __syncthreads();

        const bool diag = (ti >= 2 * qb);
        const int toff = (ti - 2 * qb) * 64;   // kv offset rel. q-tile (diag only)

        // QK^T per kv 16-block n, both strips share the K fragment.
        #pragma unroll
        for (int n = 0; n < 4; n++) {
            f32x4 s0 = (f32x4){0.f, 0.f, 0.f, 0.f};
            f32x4 s1 = (f32x4){0.f, 0.f, 0.f, 0.f};
            #pragma unroll
            for (int k = 0; k < 4; k++) {
                bf16x8 bf = *reinterpret_cast<const bf16x8*>(
                    &Ks[n * 16 + col][k * 32 + quad * 8]);
                s0 = __builtin_amdgcn_mfma_f32_16x16x32_bf16(qf[0][k], bf, s0, 0, 0, 0);
                s1 = __builtin_amdgcn_mfma_f32_16x16x32_bf16(qf[1][k], bf, s1, 0, 0, 0);
            }
            // softmax numerator + P store (per strip)
            #pragma unroll
            for (int st = 0; st < 2; st++) {
                const f32x4 sv = st ? s1 : s0;
                #pragma unroll
                for (int r = 0; r < 4; r++) {
                    float p = exp2f(fmaf(sv[r], C0, CM));
                    if (diag) {
                        int qrel = w * 32 + st * 16 + quad * 4 + r;
                        if (toff + n * 16 + col > qrel) p = 0.f;
                    }
                    l_lane[st][r] += p;
                    Ps[w][st * 16 + quad * 4 + r][n * 16 + col] = (__bf16)p;
                }
            }
        }

        // PV: V fragment shared across strips.
        bf16x8 pf0[2], pf1[2];
        #pragma unroll
        for (int ks = 0; ks < 2; ks++) {
            pf0[ks] = *reinterpret_cast<const bf16x8*>(&Ps[w][col][ks * 32 + quad * 8]);
            pf1[ks] = *reinterpret_cast<const bf16x8*>(&Ps[w][16 + col][ks * 32 + quad * 8]);
        }
        #pragma unroll
        for (int n = 0; n < 8; n++) {
            #pragma unroll
            for (int ks = 0; ks < 2; ks++) {
                bf16x8 vf = *reinterpret_cast<const bf16x8*>(
                    &Vt[n * 16 + col][ks * 32 + quad * 8]);
                o_acc[0][n] = __builtin_amdgcn_mfma_f32_16x16x32_bf16(pf0[ks], vf, o_acc[0][n], 0, 0, 0);
                o_acc[1][n] = __builtin_amdgcn_mfma_f32_16x16x32_bf16(pf1[ks], vf, o_acc[1][n], 0, 0, 0);
            }
        }
    }

    #pragma unroll
    for (int st = 0; st < 2; st++) {
        #pragma unroll
        for (int r = 0; r < 4; r++) {
            float l = row_sum16(l_lane[st][r]);
            float inv = 1.0f / l;
            int qrow = r0 + w * 32 + st * 16 + quad * 4 + r;
            __bf16* op = ao + (size_t)(b * S_ + qrow) * (H_ * HD_) + h * HD_ + col;
            #pragma unroll
            for (int n = 0; n < 8; n++)
                op[n * 16] = (__bf16)(o_acc[st][n][r] * inv);
        }
    }
}

// ---------------------------------------------------------------------------
extern "C" void kernel_launch(void* const* d_in, const int* in_sizes, int n_in,
                              void* d_out, int out_size, void* d_ws, size_t ws_size,
                              hipStream_t stream) {
    const float* x  = (const float*)d_in[0];
    const float* wq = (const float*)d_in[1];
    const float* wk = (const float*)d_in[2];
    const float* wv = (const float*)d_in[3];
    const float* wo = (const float*)d_in[4];
    const float* qw = (const float*)d_in[5];
    const float* kw = (const float*)d_in[6];
    float* out = (float*)d_out;

    // workspace (bf16 elements), total 50.33M elems = 100.66 MB
    __bf16* ws  = (__bf16*)d_ws;
    __bf16* xb  = ws;                               // [4096][2048]  8.4M
    __bf16* wb  = xb  + (size_t)8388608;            // [4096][2048]  8.4M (wq|wk|wv)
    __bf16* wob = wb  + (size_t)8388608;            // [2048][2048]  4.2M
    __bf16* qkv = wob + (size_t)4194304;            // [4096][4096] 16.8M
    __bf16* ao  = qkv + (size_t)16777216;           // [4096][2048]  8.4M
    __bf16* vtg = ao  + (size_t)8388608;            // [16][128][2048] 4.2M
    // rope table lives in the ao region (dead until attn writes it)
    float* rtab = (float*)ao;                       // [2048][128] fp32 = 1 MB

    cvt_all<<<20480, 256, 0, stream>>>(x, wq, wk, wv, wo, xb, wb, wob);
    build_rope<<<S_, 128, 0, stream>>>(rtab);

    // fused QKV projection: 256^2 8-phase (R4 schedule), 256 blocks (XCD swz)
    gemm_bf16_8ph<<<256, 512, 0, stream>>>(xb, wb, qkv, BS_, NQKV, D_);

    // RMSNorm + RoPE on q+k (24 heads x 4096 rows, 16 heads/block)
    norm_rope<<<(BS_ * 24) / 16, 256, 0, stream>>>(qkv, qw, kw, rtab);

    // global V^T
    transpose_v<<<dim3(S_ / 64, B_ * HK_), 256, 0, stream>>>(qkv, vtg);

    // causal GQA attention: 128-row q-tiles, big-first (512 blocks)
    attn_mfma<<<dim3(B_ * H_, S_ / 128), 256, 0, stream>>>(qkv, vtg, ao);

    // output projection: 128x64 tiles -> 1024 blocks (CU overlap)
    gemm_bf16_nt_n64<float><<<dim3(BS_ / 128, D_ / 64), 256, 0, stream>>>(
        ao, wob, out, BS_, D_, H_ * HD_);
}

// Round 9
// 346.911 us; speedup vs baseline: 1.0062x; 1.0062x over previous
//
#include <hip/hip_runtime.h>
#include <hip/hip_bf16.h>
#include <math.h>

// Problem constants (Qwen3-style attention block)
#define B_   2
#define S_   2048
#define D_   2048
#define H_   16
#define HK_  8
#define HD_  128
#define BS_  (B_ * S_)          // 4096 rows
#define NQKV 4096               // combined q(2048) + k(1024) + v(1024) cols
#define SCALE 0.08838834764831845f  // 1/sqrt(128)

typedef __bf16 bf16x8 __attribute__((ext_vector_type(8)));
typedef __bf16 bf16x4 __attribute__((ext_vector_type(4)));
typedef float  f32x4  __attribute__((ext_vector_type(4)));

#define AS1(p) ((const __attribute__((address_space(1))) void*)(p))
#define AS3(p) ((__attribute__((address_space(3))) void*)(p))

// 16-lane (DPP row) rotate-reduce sum: VALU latency, no LDS round-trip.
template <int S>
__device__ __forceinline__ float ror16(float x) {
    return __builtin_bit_cast(float, __builtin_amdgcn_update_dpp(
        0, __builtin_bit_cast(int, x), 0x120 | S, 0xF, 0xF, true));
}
__device__ __forceinline__ float row_sum16(float x) {
    x += ror16<8>(x);
    x += ror16<4>(x);
    x += ror16<2>(x);
    x += ror16<1>(x);
    return x;
}

// ---------------------------------------------------------------------------
// All fp32 -> bf16 converts in one launch.
// ---------------------------------------------------------------------------
__global__ __launch_bounds__(256) void cvt_all(const float* __restrict__ x,
                                               const float* __restrict__ wq,
                                               const float* __restrict__ wk,
                                               const float* __restrict__ wv,
                                               const float* __restrict__ wo,
                                               __bf16* __restrict__ xb,
                                               __bf16* __restrict__ wb,
                                               __bf16* __restrict__ wob) {
    int bid = blockIdx.x;
    const float* src;
    __bf16* dst;
    int i4;
    if (bid < 8192)       { src = x;  dst = xb;                    i4 = bid * 256; }
    else if (bid < 12288) { src = wq; dst = wb;                    i4 = (bid - 8192) * 256; }
    else if (bid < 14336) { src = wk; dst = wb + (size_t)4194304;  i4 = (bid - 12288) * 256; }
    else if (bid < 16384) { src = wv; dst = wb + (size_t)6291456;  i4 = (bid - 14336) * 256; }
    else                  { src = wo; dst = wob;                   i4 = (bid - 16384) * 256; }
    i4 += threadIdx.x;
    float4 v = reinterpret_cast<const float4*>(src)[i4];
    bf16x4 o = {(__bf16)v.x, (__bf16)v.y, (__bf16)v.z, (__bf16)v.w};
    reinterpret_cast<bf16x4*>(dst)[i4] = o;
}

// ---------------------------------------------------------------------------
// RoPE cos/sin table: tab[s][0..63]=cos(ang_i), tab[s][64..127]=sin(ang_i).
// ---------------------------------------------------------------------------
__global__ __launch_bounds__(128) void build_rope(float* __restrict__ tab) {
    int s = blockIdx.x;
    int d = threadIdx.x;
    int i = d & 63;
    float inv_freq = exp2f(-19.931568569324174f * (float)(2 * i) * (1.0f / 128.0f));
    float ang = (float)s * inv_freq;
    float sn, cs;
    sincosf(ang, &sn, &cs);
    tab[s * 128 + d] = (d < 64) ? cs : sn;
}

// ---------------------------------------------------------------------------
// 256x256 8-phase bf16 MFMA NT GEMM — R4 schedule (best measured: 82-83 µs,
// no spill). One barrier per phase: {ds_read; stg; [vmcnt]; BAR; lgkm0+schedbar;
// MFMA}. b0f/b1f double-buffered B fragments; vmcnt(4) at ph4/ph8 pre-barrier.
// ---------------------------------------------------------------------------
__global__ __launch_bounds__(512, 2) void gemm_bf16_8ph(const __bf16* __restrict__ A,
                                                        const __bf16* __restrict__ W,
                                                        __bf16* __restrict__ C,
                                                        int M, int N, int K) {
    __shared__ __bf16 lds[2][2][256 * 64];   // [buf][A=0/B=1][row*64 + chunk]

    const int t    = threadIdx.x;            // 0..511
    const int w    = t >> 6;                 // wave 0..7
    const int lane = t & 63;
    const int col  = lane & 15;
    const int quad = lane >> 4;
    const int c7   = col & 7;
    const int wm   = w >> 2;                 // 0..1  (2 M-warps, 128 rows each)
    const int wn   = w & 3;                  // 0..3  (4 N-warps, 64 cols each)

    // XCD-aware supertile swizzle (16x16 block grid, 8 XCDs, 256%8==0).
    const int bid = blockIdx.x;
    const int nid = (bid & 7) * 32 + (bid >> 3);
    const int st  = nid >> 4;
    const int wi  = nid & 15;
    const int m0 = ((st >> 2) * 4 + (wi >> 2)) * 256;
    const int n0 = ((st & 3) * 4 + (wi & 3)) * 256;

    // staging source (per-lane): wave w covers rows w*16..w*16+15 of a half
    const int lr8 = lane >> 3;                       // 0..7
    const int sw8 = ((lane & 7) ^ lr8) * 8;          // swizzled K-chunk (elems)
    const __bf16* Ag = A + (size_t)(m0 + w * 16 + lr8) * K + sw8;
    const __bf16* Wg = W + (size_t)(n0 + w * 16 + lr8) * K + sw8;

    const int nkt = K >> 6;      // number of 64-wide K-tiles (32 for K=2048)
    const int nit = nkt >> 1;    // main-loop iterations (2 K-tiles each)

    // fragment read bases (element offsets within a [256][64] panel)
    const int aBase = (wm * 128 + col) * 64;
    const int bBase = (wn * 64 + col) * 64;
    const int kx0 = (quad ^ c7) * 8;                 // kk=0 chunk offset
    const int kx1 = ((4 + quad) ^ c7) * 8;           // kk=1

    f32x4 acc[8][4];
    #pragma unroll
    for (int i = 0; i < 8; i++)
        #pragma unroll
        for (int j = 0; j < 4; j++) acc[i][j] = (f32x4){0.f, 0.f, 0.f, 0.f};

    bf16x8 a[4][2], a2[4][2], b0f[2][2], b1f[2][2];

    auto stg = [&](int ktv, int bufc, int ab, int half) {
        if (ktv >= nkt) return;
        const __bf16* gb = (ab ? Wg : Ag) + (size_t)half * 128 * K + (size_t)ktv * 64;
        __bf16* db = &lds[bufc][ab][(half * 128 + w * 16) * 64];
        __builtin_amdgcn_global_load_lds(AS1(gb), AS3(db), 16, 0, 0);
        __builtin_amdgcn_global_load_lds(AS1(gb + (size_t)8 * K), AS3(db + 512), 16, 0, 0);
    };
    auto lda = [&](bf16x8 (&dst)[4][2], const __bf16* panel, int g) {
        #pragma unroll
        for (int mi = 0; mi < 4; mi++) {
            dst[mi][0] = *reinterpret_cast<const bf16x8*>(&panel[aBase + (g * 64 + mi * 16) * 64 + kx0]);
            dst[mi][1] = *reinterpret_cast<const bf16x8*>(&panel[aBase + (g * 64 + mi * 16) * 64 + kx1]);
        }
    };
    auto ldb = [&](bf16x8 (&dst)[2][2], const __bf16* panel, int ng) {
        #pragma unroll
        for (int ni = 0; ni < 2; ni++) {
            dst[ni][0] = *reinterpret_cast<const bf16x8*>(&panel[bBase + (ng * 32 + ni * 16) * 64 + kx0]);
            dst[ni][1] = *reinterpret_cast<const bf16x8*>(&panel[bBase + (ng * 32 + ni * 16) * 64 + kx1]);
        }
    };
    auto mm = [&](bf16x8 (&af)[4][2], bf16x8 (&bfr)[2][2], int g, int ng) {
        __builtin_amdgcn_s_setprio(1);
        #pragma unroll
        for (int mi = 0; mi < 4; mi++)
            #pragma unroll
            for (int ni = 0; ni < 2; ni++) {
                f32x4 c = acc[g * 4 + mi][ng * 2 + ni];
                c = __builtin_amdgcn_mfma_f32_16x16x32_bf16(af[mi][0], bfr[ni][0], c, 0, 0, 0);
                c = __builtin_amdgcn_mfma_f32_16x16x32_bf16(af[mi][1], bfr[ni][1], c, 0, 0, 0);
                acc[g * 4 + mi][ng * 2 + ni] = c;
            }
        __builtin_amdgcn_s_setprio(0);
    };

#define BAR  __builtin_amdgcn_s_barrier()
#define LGKM0 do { asm volatile("s_waitcnt lgkmcnt(0)" ::: "memory"); \
                   __builtin_amdgcn_sched_barrier(0); } while (0)
#define VM(n) asm volatile("s_waitcnt vmcnt(" #n ")" ::: "memory")

    // ---- prologue: kt0 {A0,A1,B0,B1}, kt1 {A0,A1}; land kt0, keep 2 in flight
    stg(0, 0, 0, 0); stg(0, 0, 0, 1); stg(0, 0, 1, 0); stg(0, 0, 1, 1);
    stg(1, 1, 0, 0); stg(1, 1, 0, 1);
    VM(4);
    BAR;

    #pragma unroll 1
    for (int it = 0; it < nit; ++it) {
        const int k2 = it * 2;
        const bool last = (it == nit - 1);

        const __bf16* A0p = &lds[0][0][0];
        const __bf16* B0p = &lds[0][1][0];
        const __bf16* A1p = &lds[1][0][0];
        const __bf16* B1p = &lds[1][1][0];

        // ---- K-tile k2 (buf0): phases 1-4
        lda(a, A0p, 0); ldb(b0f, B0p, 0);
        stg(k2 + 1, 1, 1, 0);
        BAR; LGKM0;
        mm(a, b0f, 0, 0);
        lda(a2, A0p, 1);
        stg(k2 + 1, 1, 1, 1);
        BAR; LGKM0;
        mm(a2, b0f, 1, 0);
        ldb(b1f, B0p, 1);
        stg(k2 + 2, 0, 0, 0);
        BAR; LGKM0;
        mm(a, b1f, 0, 1);
        stg(k2 + 2, 0, 0, 1);
        if (last) VM(0); else VM(4);
        BAR;
        mm(a2, b1f, 1, 1);

        // ---- K-tile k2+1 (buf1): phases 5-8
        lda(a, A1p, 0); ldb(b0f, B1p, 0);
        stg(k2 + 2, 0, 1, 0);
        BAR; LGKM0;
        mm(a, b0f, 0, 0);
        lda(a2, A1p, 1);
        stg(k2 + 2, 0, 1, 1);
        BAR; LGKM0;
        mm(a2, b0f, 1, 0);
        ldb(b1f, B1p, 1);
        stg(k2 + 3, 1, 0, 0);
        BAR; LGKM0;
        mm(a, b1f, 0, 1);
        stg(k2 + 3, 1, 0, 1);
        if (!last) { VM(4); }
        BAR;
        mm(a2, b1f, 1, 1);
    }

#undef BAR
#undef LGKM0
#undef VM

    // ---- epilogue: C write (verified C/D mapping)
    #pragma unroll
    for (int m8 = 0; m8 < 8; m8++) {
        #pragma unroll
        for (int r = 0; r < 4; r++) {
            size_t row = m0 + wm * 128 + m8 * 16 + quad * 4 + r;
            __bf16* cp = C + row * N + n0 + wn * 64 + col;
            #pragma unroll
            for (int n4 = 0; n4 < 4; n4++) cp[n4 * 16] = (__bf16)acc[m8][n4][r];
        }
    }
}

// ---------------------------------------------------------------------------
// bf16 MFMA NT GEMM, 128(M)x64(N) tile: for narrow-N GEMMs where a large
// tile would leave CUs idle (out-proj: N=2048 -> 1024 blocks).
// ---------------------------------------------------------------------------
template <typename CT>
__global__ __launch_bounds__(256) void gemm_bf16_nt_n64(const __bf16* __restrict__ A,
                                                        const __bf16* __restrict__ W,
                                                        CT* __restrict__ C,
                                                        int M, int N, int K) {
    __shared__ __bf16 As[128 * 64];
    __shared__ __bf16 Bs[64 * 64];

    const int t    = threadIdx.x;
    const int w    = t >> 6;
    const int lane = t & 63;
    const int col  = lane & 15;
    const int quad = lane >> 4;
    const int wm   = w >> 1;      // 0..1 -> M half (64 rows)
    const int wn   = w & 1;       // 0..1 -> N half (32 cols)

    const int m0 = blockIdx.x * 128;
    const int n0 = blockIdx.y * 64;

    const int lrow8 = lane >> 3;
    const int lch   = ((lane & 7) ^ lrow8) * 8;

    const __bf16* agp = A + (size_t)(m0 + w * 32 + lrow8) * K + lch;
    const __bf16* wgp = W + (size_t)(n0 + w * 16 + lrow8) * K + lch;
    __bf16* alp = As + (w * 32) * 64;
    __bf16* blp = Bs + (w * 16) * 64;

    const int c7 = col & 7;

    f32x4 acc[4][2];
    #pragma unroll
    for (int m = 0; m < 4; m++)
        #pragma unroll
        for (int n = 0; n < 2; n++) acc[m][n] = (f32x4){0.f, 0.f, 0.f, 0.f};

    #pragma unroll 1
    for (int k0 = 0; k0 < K; k0 += 64) {
        #pragma unroll
        for (int j = 0; j < 4; j++)
            __builtin_amdgcn_global_load_lds(AS1(agp + k0 + (size_t)(j * 8) * K),
                                             AS3(alp + j * 512), 16, 0, 0);
        #pragma unroll
        for (int j = 0; j < 2; j++)
            __builtin_amdgcn_global_load_lds(AS1(wgp + k0 + (size_t)(j * 8) * K),
                                             AS3(blp + j * 512), 16, 0, 0);
        __syncthreads();

        #pragma unroll
        for (int kk = 0; kk < 2; kk++) {
            bf16x8 af[4], bfr[2];
            #pragma unroll
            for (int m = 0; m < 4; m++)
                af[m] = *reinterpret_cast<const bf16x8*>(
                    &As[(wm * 64 + m * 16 + col) * 64 + ((kk * 4 + quad) ^ c7) * 8]);
            #pragma unroll
            for (int n = 0; n < 2; n++)
                bfr[n] = *reinterpret_cast<const bf16x8*>(
                    &Bs[(wn * 32 + n * 16 + col) * 64 + ((kk * 4 + quad) ^ c7) * 8]);

            #pragma unroll
            for (int m = 0; m < 4; m++)
                #pragma unroll
                for (int n = 0; n < 2; n++)
                    acc[m][n] = __builtin_amdgcn_mfma_f32_16x16x32_bf16(af[m], bfr[n], acc[m][n], 0, 0, 0);
        }
        __syncthreads();
    }

    #pragma unroll
    for (int m = 0; m < 4; m++) {
        #pragma unroll
        for (int r = 0; r < 4; r++) {
            size_t row = m0 + wm * 64 + m * 16 + quad * 4 + r;
            CT* cp = C + row * N + n0 + wn * 32 + col;
            #pragma unroll
            for (int n = 0; n < 2; n++) cp[n * 16] = (CT)acc[m][n][r];
        }
    }
}

// ---------------------------------------------------------------------------
// Fused per-head RMSNorm + RoPE, vectorized: one head per 16-lane DPP row.
// ---------------------------------------------------------------------------
__global__ __launch_bounds__(256) void norm_rope(__bf16* __restrict__ qkv,
                                                 const float* __restrict__ qw,
                                                 const float* __restrict__ kw,
                                                 const float* __restrict__ tab) {
    const int g    = blockIdx.x * 16 + (threadIdx.x >> 4);  // head-instance
    const int l    = threadIdx.x & 15;
    const int row  = g / 24;
    const int head = g - row * 24;
    const int s    = row & (S_ - 1);

    const float* w = (head < H_) ? qw : kw;
    __bf16* p = qkv + (size_t)row * NQKV + head * HD_ + l * 8;

    bf16x8 xv = *reinterpret_cast<const bf16x8*>(p);
    float xf[8];
    float ss = 0.f;
    #pragma unroll
    for (int j = 0; j < 8; j++) { xf[j] = (float)xv[j]; ss = fmaf(xf[j], xf[j], ss); }
    ss = row_sum16(ss);
    float rs = rsqrtf(ss * (1.0f / 128.0f) + 1e-6f);

    // normed value (fp32)
    float nf[8];
    const float4 w0 = *reinterpret_cast<const float4*>(&w[l * 8]);
    const float4 w1 = *reinterpret_cast<const float4*>(&w[l * 8 + 4]);
    nf[0] = xf[0] * rs * w0.x; nf[1] = xf[1] * rs * w0.y;
    nf[2] = xf[2] * rs * w0.z; nf[3] = xf[3] * rs * w0.w;
    nf[4] = xf[4] * rs * w1.x; nf[5] = xf[5] * rs * w1.y;
    nf[6] = xf[6] * rs * w1.z; nf[7] = xf[7] * rs * w1.w;

    // RoPE pair values from the other half (lane l^8, same j)
    float of[8];
    #pragma unroll
    for (int j = 0; j < 8; j++) of[j] = __shfl_xor(nf[j], 8);

    // cos/sin for freq index i = (l&7)*8 + j
    const int ib = (l & 7) * 8;
    const float4 c0 = *reinterpret_cast<const float4*>(&tab[s * 128 + ib]);
    const float4 c1 = *reinterpret_cast<const float4*>(&tab[s * 128 + ib + 4]);
    const float4 s0 = *reinterpret_cast<const float4*>(&tab[s * 128 + 64 + ib]);
    const float4 s1 = *reinterpret_cast<const float4*>(&tab[s * 128 + 64 + ib + 4]);
    float cs[8] = {c0.x, c0.y, c0.z, c0.w, c1.x, c1.y, c1.z, c1.w};
    float sn[8] = {s0.x, s0.y, s0.z, s0.w, s1.x, s1.y, s1.z, s1.w};

    bf16x8 out;
    if (l < 8) {
        #pragma unroll
        for (int j = 0; j < 8; j++) out[j] = (__bf16)(nf[j] * cs[j] - of[j] * sn[j]);
    } else {
        #pragma unroll
        for (int j = 0; j < 8; j++) out[j] = (__bf16)(of[j] * sn[j] + nf[j] * cs[j]);
    }
    *reinterpret_cast<bf16x8*>(p) = out;
}

// ---------------------------------------------------------------------------
// V transpose: vt[(b*HK+kvh)*128 + dim][s] = v[b*S+s][kvh*128+dim]
// ---------------------------------------------------------------------------
__global__ __launch_bounds__(256) void transpose_v(const __bf16* __restrict__ qkv,
                                                   __bf16* __restrict__ vt) {
    __shared__ __bf16 Ls[64][136];
    const int t  = threadIdx.x;
    const int bk = blockIdx.y;            // b*8 + kvh
    const int b  = bk >> 3;
    const int kvh = bk & 7;
    const int s0 = blockIdx.x * 64;

    #pragma unroll
    for (int i = 0; i < 4; i++) {
        int f = t + i * 256;
        int row = f >> 4;
        int d8 = (f & 15) * 8;
        bf16x8 v = *reinterpret_cast<const bf16x8*>(
            &qkv[(size_t)(b * S_ + s0 + row) * NQKV + 3072 + kvh * HD_ + d8]);
        *reinterpret_cast<bf16x8*>(&Ls[row][d8]) = v;
    }
    __syncthreads();

    #pragma unroll
    for (int i = 0; i < 4; i++) {
        int f = t + i * 256;
        int dim = f >> 3;
        int kc = f & 7;
        bf16x8 o;
        #pragma unroll
        for (int e = 0; e < 8; e++) o[e] = Ls[kc * 8 + e][dim];
        *reinterpret_cast<bf16x8*>(
            &vt[((size_t)bk * HD_ + dim) * S_ + s0 + kc * 8]) = o;
    }
}

// ---------------------------------------------------------------------------
// MFMA bf16 flash attention (causal, GQA), fixed-max softmax.
// R9: QBLK=128 with 8 WAVES x 16 q-rows (R8 post-mortem: 4-wave QBLK=128 was
// occupancy-starved at 13% — 512-block grid needs 8 waves/block to reach
// 16 waves/CU). Per-wave structure identical to the proven QBLK=64 kernel
// (qf[4], 16 QK + 16 PV MFMA, Ps[w][16][72]); staging split over 512 threads
// (2 slots/thread). Q frags direct from global (prologue, L2-hot, verified R8).
// LDS: Ks 17408 + Vt 18432 + Ps[8][16][72] 18432 = 54272 B -> 2 blocks/CU
// (grid-limited), 16 waves/CU.
// Grid: (B*H, S/128), big q-tiles first.
// ---------------------------------------------------------------------------
__global__ __launch_bounds__(512, 4) void attn_mfma(const __bf16* __restrict__ qkv,
                                                    const __bf16* __restrict__ vt,
                                                    __bf16* __restrict__ ao) {
    __shared__ __bf16 Ks[64][136];
    __shared__ __bf16 Vt[128][72];
    __shared__ __bf16 Ps[8][16][72];

    const int t    = threadIdx.x;          // 0..511
    const int w    = t >> 6;               // wave 0..7
    const int lane = t & 63;
    const int col  = lane & 15;
    const int quad = lane >> 4;

    const int bh  = blockIdx.x;
    const int b   = bh >> 4;
    const int h   = bh & 15;
    const int kvh = h >> 1;
    const int qb  = gridDim.y - 1 - blockIdx.y;   // big q-tiles first
    const int r0  = qb * 128;

    const float C0 = SCALE * 1.44269504f;
    const float CM = -12.0f * 1.44269504f;

    const __bf16* vbase = vt + ((size_t)(b * HK_ + kvh) * HD_) * S_;

    // K/V staging slots (per-thread, 2 each; 512 threads cover 64x16 + 128x8)
    const __bf16* kp[2];
    __bf16*       kw_[2];
    const __bf16* vp[2];
    __bf16*       vw_[2];
    #pragma unroll
    for (int i = 0; i < 2; i++) {
        int f = t + i * 512;
        int row = f >> 4, d8 = (f & 15) * 8;
        kp[i]  = qkv + (size_t)(b * S_ + row) * NQKV + 2048 + kvh * HD_ + d8;
        kw_[i] = &Ks[row][d8];
        int dim = f >> 3, kc = f & 7;
        vp[i]  = vbase + (size_t)dim * S_ + kc * 8;
        vw_[i] = &Vt[dim][kc * 8];
    }

    bf16x8 kreg[2], vreg[2];
    #pragma unroll
    for (int i = 0; i < 2; i++) {
        kreg[i] = *reinterpret_cast<const bf16x8*>(kp[i]);  kp[i] += (size_t)64 * NQKV;
        vreg[i] = *reinterpret_cast<const bf16x8*>(vp[i]);  vp[i] += 64;
    }

    // Q fragments direct from global: wave w owns q rows r0 + w*16 + (0..15).
    bf16x8 qf[4];
    #pragma unroll
    for (int k = 0; k < 4; k++)
        qf[k] = *reinterpret_cast<const bf16x8*>(
            &qkv[(size_t)(b * S_ + r0 + w * 16 + col) * NQKV
                 + h * HD_ + k * 32 + quad * 8]);

    f32x4 o_acc[8];
    #pragma unroll
    for (int i = 0; i < 8; i++) o_acc[i] = (f32x4){0.f, 0.f, 0.f, 0.f};
    float l_lane[4] = {0.f, 0.f, 0.f, 0.f};

    const int ntiles = 2 * qb + 2;
    for (int ti = 0; ti < ntiles; ti++) {
        __syncthreads();

        #pragma unroll
        for (int i = 0; i < 2; i++) {
            *reinterpret_cast<bf16x8*>(kw_[i]) = kreg[i];
            *reinterpret_cast<bf16x8*>(vw_[i]) = vreg[i];
        }
        if (ti + 1 < ntiles) {
            #pragma unroll
            for (int i = 0; i < 2; i++) {
                kreg[i] = *reinterpret_cast<const bf16x8*>(kp[i]);  kp[i] += (size_t)64 * NQKV;
                vreg[i] = *reinterpret_cast<const bf16x8*>(vp[i]);  vp[i] += 64;
            }
        }
        __syncthreads();

        const bool diag = (ti >= 2 * qb);
        const int toff = (ti - 2 * qb) * 64;   // kv offset rel. q-tile (diag only)

        f32x4 s[4];
        #pragma unroll
        for (int n = 0; n < 4; n++) {
            f32x4 acc = (f32x4){0.f, 0.f, 0.f, 0.f};
            #pragma unroll
            for (int k = 0; k < 4; k++) {
                bf16x8 bf = *reinterpret_cast<const bf16x8*>(
                    &Ks[n * 16 + col][k * 32 + quad * 8]);
                acc = __builtin_amdgcn_mfma_f32_16x16x32_bf16(qf[k], bf, acc, 0, 0, 0);
            }
            s[n] = acc;
        }

        #pragma unroll
        for (int r = 0; r < 4; r++) {
            float p0 = exp2f(fmaf(s[0][r], C0, CM));
            float p1 = exp2f(fmaf(s[1][r], C0, CM));
            float p2 = exp2f(fmaf(s[2][r], C0, CM));
            float p3 = exp2f(fmaf(s[3][r], C0, CM));
            if (diag) {
                int qrel = w * 16 + quad * 4 + r;   // q row within 128-tile
                if (toff + 0 * 16 + col > qrel) p0 = 0.f;
                if (toff + 1 * 16 + col > qrel) p1 = 0.f;
                if (toff + 2 * 16 + col > qrel) p2 = 0.f;
                if (toff + 3 * 16 + col > qrel) p3 = 0.f;
            }
            l_lane[r] += p0 + p1 + p2 + p3;
            Ps[w][quad * 4 + r][0 * 16 + col] = (__bf16)p0;
            Ps[w][quad * 4 + r][1 * 16 + col] = (__bf16)p1;
            Ps[w][quad * 4 + r][2 * 16 + col] = (__bf16)p2;
            Ps[w][quad * 4 + r][3 * 16 + col] = (__bf16)p3;
        }

        bf16x8 pf[2];
        #pragma unroll
        for (int ks = 0; ks < 2; ks++)
            pf[ks] = *reinterpret_cast<const bf16x8*>(&Ps[w][col][ks * 32 + quad * 8]);
        #pragma unroll
        for (int n = 0; n < 8; n++) {
            #pragma unroll
            for (int ks = 0; ks < 2; ks++) {
                bf16x8 vf = *reinterpret_cast<const bf16x8*>(
                    &Vt[n * 16 + col][ks * 32 + quad * 8]);
                o_acc[n] = __builtin_amdgcn_mfma_f32_16x16x32_bf16(pf[ks], vf, o_acc[n], 0, 0, 0);
            }
        }
    }

    #pragma unroll
    for (int r = 0; r < 4; r++) {
        float l = row_sum16(l_lane[r]);
        float inv = 1.0f / l;
        int qrow = r0 + w * 16 + quad * 4 + r;
        __bf16* op = ao + (size_t)(b * S_ + qrow) * (H_ * HD_) + h * HD_ + col;
        #pragma unroll
        for (int n = 0; n < 8; n++)
            op[n * 16] = (__bf16)(o_acc[n][r] * inv);
    }
}

// ---------------------------------------------------------------------------
extern "C" void kernel_launch(void* const* d_in, const int* in_sizes, int n_in,
                              void* d_out, int out_size, void* d_ws, size_t ws_size,
                              hipStream_t stream) {
    const float* x  = (const float*)d_in[0];
    const float* wq = (const float*)d_in[1];
    const float* wk = (const float*)d_in[2];
    const float* wv = (const float*)d_in[3];
    const float* wo = (const float*)d_in[4];
    const float* qw = (const float*)d_in[5];
    const float* kw = (const float*)d_in[6];
    float* out = (float*)d_out;

    // workspace (bf16 elements), total 50.33M elems = 100.66 MB
    __bf16* ws  = (__bf16*)d_ws;
    __bf16* xb  = ws;                               // [4096][2048]  8.4M
    __bf16* wb  = xb  + (size_t)8388608;            // [4096][2048]  8.4M (wq|wk|wv)
    __bf16* wob = wb  + (size_t)8388608;            // [2048][2048]  4.2M
    __bf16* qkv = wob + (size_t)4194304;            // [4096][4096] 16.8M
    __bf16* ao  = qkv + (size_t)16777216;           // [4096][2048]  8.4M
    __bf16* vtg = ao  + (size_t)8388608;            // [16][128][2048] 4.2M
    // rope table lives in the ao region (dead until attn writes it)
    float* rtab = (float*)ao;                       // [2048][128] fp32 = 1 MB

    cvt_all<<<20480, 256, 0, stream>>>(x, wq, wk, wv, wo, xb, wb, wob);
    build_rope<<<S_, 128, 0, stream>>>(rtab);

    // fused QKV projection: 256^2 8-phase (R4 schedule), 256 blocks (XCD swz)
    gemm_bf16_8ph<<<256, 512, 0, stream>>>(xb, wb, qkv, BS_, NQKV, D_);

    // RMSNorm + RoPE on q+k (24 heads x 4096 rows, 16 heads/block)
    norm_rope<<<(BS_ * 24) / 16, 256, 0, stream>>>(qkv, qw, kw, rtab);

    // global V^T
    transpose_v<<<dim3(S_ / 64, B_ * HK_), 256, 0, stream>>>(qkv, vtg);

    // causal GQA attention: 128-row q-tiles, 8 waves, big-first (512 blocks)
    attn_mfma<<<dim3(B_ * H_, S_ / 128), 512, 0, stream>>>(qkv, vtg, ao);

    // output projection: 128x64 tiles -> 1024 blocks (CU overlap)
    gemm_bf16_nt_n64<float><<<dim3(BS_ / 128, D_ / 64), 256, 0, stream>>>(
        ao, wob, out, BS_, D_, H_ * HD_);
}

// Round 10
// 327.744 us; speedup vs baseline: 1.0651x; 1.0585x over previous
//
#include <hip/hip_runtime.h>
#include <hip/hip_bf16.h>
#include <math.h>

// Problem constants (Qwen3-style attention block)
#define B_   2
#define S_   2048
#define D_   2048
#define H_   16
#define HK_  8
#define HD_  128
#define BS_  (B_ * S_)          // 4096 rows
#define NQKV 4096               // combined q(2048) + k(1024) + v(1024) cols
#define SCALE 0.08838834764831845f  // 1/sqrt(128)

typedef __bf16 bf16x8 __attribute__((ext_vector_type(8)));
typedef __bf16 bf16x4 __attribute__((ext_vector_type(4)));
typedef float  f32x4  __attribute__((ext_vector_type(4)));

#define AS1(p) ((const __attribute__((address_space(1))) void*)(p))
#define AS3(p) ((__attribute__((address_space(3))) void*)(p))

// 16-lane (DPP row) rotate-reduce sum: VALU latency, no LDS round-trip.
template <int S>
__device__ __forceinline__ float ror16(float x) {
    return __builtin_bit_cast(float, __builtin_amdgcn_update_dpp(
        0, __builtin_bit_cast(int, x), 0x120 | S, 0xF, 0xF, true));
}
__device__ __forceinline__ float row_sum16(float x) {
    x += ror16<8>(x);
    x += ror16<4>(x);
    x += ror16<2>(x);
    x += ror16<1>(x);
    return x;
}

// ---------------------------------------------------------------------------
// All fp32 -> bf16 converts in one launch.
// ---------------------------------------------------------------------------
__global__ __launch_bounds__(256) void cvt_all(const float* __restrict__ x,
                                               const float* __restrict__ wq,
                                               const float* __restrict__ wk,
                                               const float* __restrict__ wv,
                                               const float* __restrict__ wo,
                                               __bf16* __restrict__ xb,
                                               __bf16* __restrict__ wb,
                                               __bf16* __restrict__ wob) {
    int bid = blockIdx.x;
    const float* src;
    __bf16* dst;
    int i4;
    if (bid < 8192)       { src = x;  dst = xb;                    i4 = bid * 256; }
    else if (bid < 12288) { src = wq; dst = wb;                    i4 = (bid - 8192) * 256; }
    else if (bid < 14336) { src = wk; dst = wb + (size_t)4194304;  i4 = (bid - 12288) * 256; }
    else if (bid < 16384) { src = wv; dst = wb + (size_t)6291456;  i4 = (bid - 14336) * 256; }
    else                  { src = wo; dst = wob;                   i4 = (bid - 16384) * 256; }
    i4 += threadIdx.x;
    float4 v = reinterpret_cast<const float4*>(src)[i4];
    bf16x4 o = {(__bf16)v.x, (__bf16)v.y, (__bf16)v.z, (__bf16)v.w};
    reinterpret_cast<bf16x4*>(dst)[i4] = o;
}

// ---------------------------------------------------------------------------
// RoPE cos/sin table: tab[s][0..63]=cos(ang_i), tab[s][64..127]=sin(ang_i).
// ---------------------------------------------------------------------------
__global__ __launch_bounds__(128) void build_rope(float* __restrict__ tab) {
    int s = blockIdx.x;
    int d = threadIdx.x;
    int i = d & 63;
    float inv_freq = exp2f(-19.931568569324174f * (float)(2 * i) * (1.0f / 128.0f));
    float ang = (float)s * inv_freq;
    float sn, cs;
    sincosf(ang, &sn, &cs);
    tab[s * 128 + d] = (d < 64) ? cs : sn;
}

// ---------------------------------------------------------------------------
// 256x256 8-phase bf16 MFMA NT GEMM — R4 schedule (best measured: 82-83 µs,
// no spill). One barrier per phase: {ds_read; stg; [vmcnt]; BAR; lgkm0+schedbar;
// MFMA}. b0f/b1f double-buffered B fragments; vmcnt(4) at ph4/ph8 pre-barrier.
// ---------------------------------------------------------------------------
__global__ __launch_bounds__(512, 2) void gemm_bf16_8ph(const __bf16* __restrict__ A,
                                                        const __bf16* __restrict__ W,
                                                        __bf16* __restrict__ C,
                                                        int M, int N, int K) {
    __shared__ __bf16 lds[2][2][256 * 64];   // [buf][A=0/B=1][row*64 + chunk]

    const int t    = threadIdx.x;            // 0..511
    const int w    = t >> 6;                 // wave 0..7
    const int lane = t & 63;
    const int col  = lane & 15;
    const int quad = lane >> 4;
    const int c7   = col & 7;
    const int wm   = w >> 2;                 // 0..1  (2 M-warps, 128 rows each)
    const int wn   = w & 3;                  // 0..3  (4 N-warps, 64 cols each)

    // XCD-aware supertile swizzle (16x16 block grid, 8 XCDs, 256%8==0).
    const int bid = blockIdx.x;
    const int nid = (bid & 7) * 32 + (bid >> 3);
    const int st  = nid >> 4;
    const int wi  = nid & 15;
    const int m0 = ((st >> 2) * 4 + (wi >> 2)) * 256;
    const int n0 = ((st & 3) * 4 + (wi & 3)) * 256;

    // staging source (per-lane): wave w covers rows w*16..w*16+15 of a half
    const int lr8 = lane >> 3;                       // 0..7
    const int sw8 = ((lane & 7) ^ lr8) * 8;          // swizzled K-chunk (elems)
    const __bf16* Ag = A + (size_t)(m0 + w * 16 + lr8) * K + sw8;
    const __bf16* Wg = W + (size_t)(n0 + w * 16 + lr8) * K + sw8;

    const int nkt = K >> 6;      // number of 64-wide K-tiles (32 for K=2048)
    const int nit = nkt >> 1;    // main-loop iterations (2 K-tiles each)

    // fragment read bases (element offsets within a [256][64] panel)
    const int aBase = (wm * 128 + col) * 64;
    const int bBase = (wn * 64 + col) * 64;
    const int kx0 = (quad ^ c7) * 8;                 // kk=0 chunk offset
    const int kx1 = ((4 + quad) ^ c7) * 8;           // kk=1

    f32x4 acc[8][4];
    #pragma unroll
    for (int i = 0; i < 8; i++)
        #pragma unroll
        for (int j = 0; j < 4; j++) acc[i][j] = (f32x4){0.f, 0.f, 0.f, 0.f};

    bf16x8 a[4][2], a2[4][2], b0f[2][2], b1f[2][2];

    auto stg = [&](int ktv, int bufc, int ab, int half) {
        if (ktv >= nkt) return;
        const __bf16* gb = (ab ? Wg : Ag) + (size_t)half * 128 * K + (size_t)ktv * 64;
        __bf16* db = &lds[bufc][ab][(half * 128 + w * 16) * 64];
        __builtin_amdgcn_global_load_lds(AS1(gb), AS3(db), 16, 0, 0);
        __builtin_amdgcn_global_load_lds(AS1(gb + (size_t)8 * K), AS3(db + 512), 16, 0, 0);
    };
    auto lda = [&](bf16x8 (&dst)[4][2], const __bf16* panel, int g) {
        #pragma unroll
        for (int mi = 0; mi < 4; mi++) {
            dst[mi][0] = *reinterpret_cast<const bf16x8*>(&panel[aBase + (g * 64 + mi * 16) * 64 + kx0]);
            dst[mi][1] = *reinterpret_cast<const bf16x8*>(&panel[aBase + (g * 64 + mi * 16) * 64 + kx1]);
        }
    };
    auto ldb = [&](bf16x8 (&dst)[2][2], const __bf16* panel, int ng) {
        #pragma unroll
        for (int ni = 0; ni < 2; ni++) {
            dst[ni][0] = *reinterpret_cast<const bf16x8*>(&panel[bBase + (ng * 32 + ni * 16) * 64 + kx0]);
            dst[ni][1] = *reinterpret_cast<const bf16x8*>(&panel[bBase + (ng * 32 + ni * 16) * 64 + kx1]);
        }
    };
    auto mm = [&](bf16x8 (&af)[4][2], bf16x8 (&bfr)[2][2], int g, int ng) {
        __builtin_amdgcn_s_setprio(1);
        #pragma unroll
        for (int mi = 0; mi < 4; mi++)
            #pragma unroll
            for (int ni = 0; ni < 2; ni++) {
                f32x4 c = acc[g * 4 + mi][ng * 2 + ni];
                c = __builtin_amdgcn_mfma_f32_16x16x32_bf16(af[mi][0], bfr[ni][0], c, 0, 0, 0);
                c = __builtin_amdgcn_mfma_f32_16x16x32_bf16(af[mi][1], bfr[ni][1], c, 0, 0, 0);
                acc[g * 4 + mi][ng * 2 + ni] = c;
            }
        __builtin_amdgcn_s_setprio(0);
    };

#define BAR  __builtin_amdgcn_s_barrier()
#define LGKM0 do { asm volatile("s_waitcnt lgkmcnt(0)" ::: "memory"); \
                   __builtin_amdgcn_sched_barrier(0); } while (0)
#define VM(n) asm volatile("s_waitcnt vmcnt(" #n ")" ::: "memory")

    // ---- prologue: kt0 {A0,A1,B0,B1}, kt1 {A0,A1}; land kt0, keep 2 in flight
    stg(0, 0, 0, 0); stg(0, 0, 0, 1); stg(0, 0, 1, 0); stg(0, 0, 1, 1);
    stg(1, 1, 0, 0); stg(1, 1, 0, 1);
    VM(4);
    BAR;

    #pragma unroll 1
    for (int it = 0; it < nit; ++it) {
        const int k2 = it * 2;
        const bool last = (it == nit - 1);

        const __bf16* A0p = &lds[0][0][0];
        const __bf16* B0p = &lds[0][1][0];
        const __bf16* A1p = &lds[1][0][0];
        const __bf16* B1p = &lds[1][1][0];

        // ---- K-tile k2 (buf0): phases 1-4
        lda(a, A0p, 0); ldb(b0f, B0p, 0);
        stg(k2 + 1, 1, 1, 0);
        BAR; LGKM0;
        mm(a, b0f, 0, 0);
        lda(a2, A0p, 1);
        stg(k2 + 1, 1, 1, 1);
        BAR; LGKM0;
        mm(a2, b0f, 1, 0);
        ldb(b1f, B0p, 1);
        stg(k2 + 2, 0, 0, 0);
        BAR; LGKM0;
        mm(a, b1f, 0, 1);
        stg(k2 + 2, 0, 0, 1);
        if (last) VM(0); else VM(4);
        BAR;
        mm(a2, b1f, 1, 1);

        // ---- K-tile k2+1 (buf1): phases 5-8
        lda(a, A1p, 0); ldb(b0f, B1p, 0);
        stg(k2 + 2, 0, 1, 0);
        BAR; LGKM0;
        mm(a, b0f, 0, 0);
        lda(a2, A1p, 1);
        stg(k2 + 2, 0, 1, 1);
        BAR; LGKM0;
        mm(a2, b0f, 1, 0);
        ldb(b1f, B1p, 1);
        stg(k2 + 3, 1, 0, 0);
        BAR; LGKM0;
        mm(a, b1f, 0, 1);
        stg(k2 + 3, 1, 0, 1);
        if (!last) { VM(4); }
        BAR;
        mm(a2, b1f, 1, 1);
    }

#undef BAR
#undef LGKM0
#undef VM

    // ---- epilogue: C write (verified C/D mapping)
    #pragma unroll
    for (int m8 = 0; m8 < 8; m8++) {
        #pragma unroll
        for (int r = 0; r < 4; r++) {
            size_t row = m0 + wm * 128 + m8 * 16 + quad * 4 + r;
            __bf16* cp = C + row * N + n0 + wn * 64 + col;
            #pragma unroll
            for (int n4 = 0; n4 < 4; n4++) cp[n4 * 16] = (__bf16)acc[m8][n4][r];
        }
    }
}

// ---------------------------------------------------------------------------
// bf16 MFMA NT GEMM: C[M,N] = A[M,K] * W[N,K]^T
// 128x128 tile, BK=64, 256 threads = 4 waves (2x2), global_load_lds width=16.
// XOR-swizzled LDS (conflict-free, verified). Used for out-proj (R10):
// 2x the arithmetic intensity of the previous 128x64 tile; N=2048 ->
// grid 16x32 = 512 blocks (2/CU co-resident).
// ---------------------------------------------------------------------------
template <typename CT>
__global__ __launch_bounds__(256) void gemm_bf16_nt(const __bf16* __restrict__ A,
                                                    const __bf16* __restrict__ W,
                                                    CT* __restrict__ C,
                                                    int M, int N, int K) {
    __shared__ __bf16 As[128 * 64];
    __shared__ __bf16 Bs[128 * 64];

    const int t    = threadIdx.x;
    const int w    = t >> 6;
    const int lane = t & 63;
    const int col  = lane & 15;
    const int quad = lane >> 4;
    const int wm   = w >> 1;
    const int wn   = w & 1;

    const int m0 = blockIdx.y * 128;
    const int n0 = blockIdx.x * 128;

    const int lrow8 = lane >> 3;                     // 0..7
    const int lch   = ((lane & 7) ^ lrow8) * 8;      // swizzled K-chunk

    const __bf16* agp = A + (size_t)(m0 + w * 32 + lrow8) * K + lch;
    const __bf16* wgp = W + (size_t)(n0 + w * 32 + lrow8) * K + lch;
    __bf16* alp = As + (w * 32) * 64;
    __bf16* blp = Bs + (w * 32) * 64;

    const int c7 = col & 7;

    f32x4 acc[4][4];
    #pragma unroll
    for (int m = 0; m < 4; m++)
        #pragma unroll
        for (int n = 0; n < 4; n++) acc[m][n] = (f32x4){0.f, 0.f, 0.f, 0.f};

    #pragma unroll 1
    for (int k0 = 0; k0 < K; k0 += 64) {
        #pragma unroll
        for (int j = 0; j < 4; j++) {
            __builtin_amdgcn_global_load_lds(AS1(agp + k0 + (size_t)(j * 8) * K),
                                             AS3(alp + j * 512), 16, 0, 0);
            __builtin_amdgcn_global_load_lds(AS1(wgp + k0 + (size_t)(j * 8) * K),
                                             AS3(blp + j * 512), 16, 0, 0);
        }
        __syncthreads();

        #pragma unroll
        for (int kk = 0; kk < 2; kk++) {
            bf16x8 af[4], bfr[4];
            #pragma unroll
            for (int m = 0; m < 4; m++)
                af[m] = *reinterpret_cast<const bf16x8*>(
                    &As[(wm * 64 + m * 16 + col) * 64 + ((kk * 4 + quad) ^ c7) * 8]);
            #pragma unroll
            for (int n = 0; n < 4; n++)
                bfr[n] = *reinterpret_cast<const bf16x8*>(
                    &Bs[(wn * 64 + n * 16 + col) * 64 + ((kk * 4 + quad) ^ c7) * 8]);

            #pragma unroll
            for (int m = 0; m < 4; m++)
                #pragma unroll
                for (int n = 0; n < 4; n++)
                    acc[m][n] = __builtin_amdgcn_mfma_f32_16x16x32_bf16(af[m], bfr[n], acc[m][n], 0, 0, 0);
        }
        __syncthreads();
    }

    #pragma unroll
    for (int m = 0; m < 4; m++) {
        #pragma unroll
        for (int r = 0; r < 4; r++) {
            size_t row = m0 + wm * 64 + m * 16 + quad * 4 + r;
            CT* cp = C + row * N + n0 + wn * 64 + col;
            #pragma unroll
            for (int n = 0; n < 4; n++) cp[n * 16] = (CT)acc[m][n][r];
        }
    }
}

// ---------------------------------------------------------------------------
// Fused per-head RMSNorm + RoPE, vectorized: one head per 16-lane DPP row.
// ---------------------------------------------------------------------------
__global__ __launch_bounds__(256) void norm_rope(__bf16* __restrict__ qkv,
                                                 const float* __restrict__ qw,
                                                 const float* __restrict__ kw,
                                                 const float* __restrict__ tab) {
    const int g    = blockIdx.x * 16 + (threadIdx.x >> 4);  // head-instance
    const int l    = threadIdx.x & 15;
    const int row  = g / 24;
    const int head = g - row * 24;
    const int s    = row & (S_ - 1);

    const float* w = (head < H_) ? qw : kw;
    __bf16* p = qkv + (size_t)row * NQKV + head * HD_ + l * 8;

    bf16x8 xv = *reinterpret_cast<const bf16x8*>(p);
    float xf[8];
    float ss = 0.f;
    #pragma unroll
    for (int j = 0; j < 8; j++) { xf[j] = (float)xv[j]; ss = fmaf(xf[j], xf[j], ss); }
    ss = row_sum16(ss);
    float rs = rsqrtf(ss * (1.0f / 128.0f) + 1e-6f);

    // normed value (fp32)
    float nf[8];
    const float4 w0 = *reinterpret_cast<const float4*>(&w[l * 8]);
    const float4 w1 = *reinterpret_cast<const float4*>(&w[l * 8 + 4]);
    nf[0] = xf[0] * rs * w0.x; nf[1] = xf[1] * rs * w0.y;
    nf[2] = xf[2] * rs * w0.z; nf[3] = xf[3] * rs * w0.w;
    nf[4] = xf[4] * rs * w1.x; nf[5] = xf[5] * rs * w1.y;
    nf[6] = xf[6] * rs * w1.z; nf[7] = xf[7] * rs * w1.w;

    // RoPE pair values from the other half (lane l^8, same j)
    float of[8];
    #pragma unroll
    for (int j = 0; j < 8; j++) of[j] = __shfl_xor(nf[j], 8);

    // cos/sin for freq index i = (l&7)*8 + j
    const int ib = (l & 7) * 8;
    const float4 c0 = *reinterpret_cast<const float4*>(&tab[s * 128 + ib]);
    const float4 c1 = *reinterpret_cast<const float4*>(&tab[s * 128 + ib + 4]);
    const float4 s0 = *reinterpret_cast<const float4*>(&tab[s * 128 + 64 + ib]);
    const float4 s1 = *reinterpret_cast<const float4*>(&tab[s * 128 + 64 + ib + 4]);
    float cs[8] = {c0.x, c0.y, c0.z, c0.w, c1.x, c1.y, c1.z, c1.w};
    float sn[8] = {s0.x, s0.y, s0.z, s0.w, s1.x, s1.y, s1.z, s1.w};

    bf16x8 out;
    if (l < 8) {
        #pragma unroll
        for (int j = 0; j < 8; j++) out[j] = (__bf16)(nf[j] * cs[j] - of[j] * sn[j]);
    } else {
        #pragma unroll
        for (int j = 0; j < 8; j++) out[j] = (__bf16)(of[j] * sn[j] + nf[j] * cs[j]);
    }
    *reinterpret_cast<bf16x8*>(p) = out;
}

// ---------------------------------------------------------------------------
// V transpose: vt[(b*HK+kvh)*128 + dim][s] = v[b*S+s][kvh*128+dim]
// ---------------------------------------------------------------------------
__global__ __launch_bounds__(256) void transpose_v(const __bf16* __restrict__ qkv,
                                                   __bf16* __restrict__ vt) {
    __shared__ __bf16 Ls[64][136];
    const int t  = threadIdx.x;
    const int bk = blockIdx.y;            // b*8 + kvh
    const int b  = bk >> 3;
    const int kvh = bk & 7;
    const int s0 = blockIdx.x * 64;

    #pragma unroll
    for (int i = 0; i < 4; i++) {
        int f = t + i * 256;
        int row = f >> 4;
        int d8 = (f & 15) * 8;
        bf16x8 v = *reinterpret_cast<const bf16x8*>(
            &qkv[(size_t)(b * S_ + s0 + row) * NQKV + 3072 + kvh * HD_ + d8]);
        *reinterpret_cast<bf16x8*>(&Ls[row][d8]) = v;
    }
    __syncthreads();

    #pragma unroll
    for (int i = 0; i < 4; i++) {
        int f = t + i * 256;
        int dim = f >> 3;
        int kc = f & 7;
        bf16x8 o;
        #pragma unroll
        for (int e = 0; e < 8; e++) o[e] = Ls[kc * 8 + e][dim];
        *reinterpret_cast<bf16x8*>(
            &vt[((size_t)bk * HD_ + dim) * S_ + s0 + kc * 8]) = o;
    }
}

// ---------------------------------------------------------------------------
// MFMA bf16 flash attention (causal, GQA rep=2), fixed-max softmax.
// R4's exact kernel (best measured config): QBLK=64, 4 waves, 1024 blocks,
// 3 blocks/CU (LDS 45056 B), big q-tiles dispatched first.
// R8/R9's QBLK=128 variants were slower (87-93 µs vs <82): causal load
// imbalance at 512 fully-resident blocks (time = longest block).
// ---------------------------------------------------------------------------
__global__ __launch_bounds__(256) void attn_mfma(const __bf16* __restrict__ qkv,
                                                 const __bf16* __restrict__ vt,
                                                 __bf16* __restrict__ ao) {
    __shared__ __align__(16) char smem[17408];
    __bf16 (*Qs)[136] = reinterpret_cast<__bf16(*)[136]>(smem);
    __bf16 (*Ks)[136] = reinterpret_cast<__bf16(*)[136]>(smem);
    __shared__ __bf16 Vt[128][72];
    __shared__ __bf16 Ps[4][16][72];

    const int t    = threadIdx.x;
    const int w    = t >> 6;
    const int lane = t & 63;
    const int col  = lane & 15;
    const int quad = lane >> 4;

    const int bh  = blockIdx.x;
    const int b   = bh >> 4;
    const int h   = bh & 15;
    const int kvh = h >> 1;
    const int qb  = gridDim.y - 1 - blockIdx.y;   // big q-tiles first
    const int r0  = qb * 64;

    const float C0 = SCALE * 1.44269504f;
    const float CM = -12.0f * 1.44269504f;

    const __bf16* vbase = vt + ((size_t)(b * HK_ + kvh) * HD_) * S_;

    const __bf16* kp[4];
    __bf16*       kw_[4];
    const __bf16* vp[4];
    __bf16*       vw_[4];
    #pragma unroll
    for (int i = 0; i < 4; i++) {
        int f = t + i * 256;
        int row = f >> 4, d8 = (f & 15) * 8;
        kp[i]  = qkv + (size_t)(b * S_ + row) * NQKV + 2048 + kvh * HD_ + d8;
        kw_[i] = &Ks[row][d8];
        int dim = f >> 3, kc = f & 7;
        vp[i]  = vbase + (size_t)dim * S_ + kc * 8;
        vw_[i] = &Vt[dim][kc * 8];
    }

    bf16x8 kreg[4], vreg[4];
    #pragma unroll
    for (int i = 0; i < 4; i++) {
        kreg[i] = *reinterpret_cast<const bf16x8*>(kp[i]);  kp[i] += (size_t)64 * NQKV;
        vreg[i] = *reinterpret_cast<const bf16x8*>(vp[i]);  vp[i] += 64;
    }

    #pragma unroll
    for (int i = 0; i < 4; i++) {
        int f   = t + i * 256;
        int row = f >> 4;
        int d8  = (f & 15) * 8;
        bf16x8 v = *reinterpret_cast<const bf16x8*>(
            &qkv[(size_t)(b * S_ + r0 + row) * NQKV + h * HD_ + d8]);
        *reinterpret_cast<bf16x8*>(&Qs[row][d8]) = v;
    }
    __syncthreads();

    bf16x8 qf[4];
    {
        const int m = w * 16 + col;
        #pragma unroll
        for (int k = 0; k < 4; k++)
            qf[k] = *reinterpret_cast<const bf16x8*>(&Qs[m][k * 32 + quad * 8]);
    }

    f32x4 o_acc[8];
    #pragma unroll
    for (int i = 0; i < 8; i++) o_acc[i] = (f32x4){0.f, 0.f, 0.f, 0.f};
    float l_lane[4] = {0.f, 0.f, 0.f, 0.f};

    const int ntiles = qb + 1;
    for (int ti = 0; ti < ntiles; ti++) {
        __syncthreads();

        #pragma unroll
        for (int i = 0; i < 4; i++) {
            *reinterpret_cast<bf16x8*>(kw_[i]) = kreg[i];
            *reinterpret_cast<bf16x8*>(vw_[i]) = vreg[i];
        }
        if (ti + 1 < ntiles) {
            #pragma unroll
            for (int i = 0; i < 4; i++) {
                kreg[i] = *reinterpret_cast<const bf16x8*>(kp[i]);  kp[i] += (size_t)64 * NQKV;
                vreg[i] = *reinterpret_cast<const bf16x8*>(vp[i]);  vp[i] += 64;
            }
        }
        __syncthreads();

        f32x4 s[4];
        #pragma unroll
        for (int n = 0; n < 4; n++) {
            f32x4 acc = (f32x4){0.f, 0.f, 0.f, 0.f};
            #pragma unroll
            for (int k = 0; k < 4; k++) {
                bf16x8 bf = *reinterpret_cast<const bf16x8*>(
                    &Ks[n * 16 + col][k * 32 + quad * 8]);
                acc = __builtin_amdgcn_mfma_f32_16x16x32_bf16(qf[k], bf, acc, 0, 0, 0);
            }
            s[n] = acc;
        }

        const bool diag = (ti == qb);
        #pragma unroll
        for (int r = 0; r < 4; r++) {
            float p0 = exp2f(fmaf(s[0][r], C0, CM));
            float p1 = exp2f(fmaf(s[1][r], C0, CM));
            float p2 = exp2f(fmaf(s[2][r], C0, CM));
            float p3 = exp2f(fmaf(s[3][r], C0, CM));
            if (diag) {
                int qloc = w * 16 + quad * 4 + r;
                if (0 * 16 + col > qloc) p0 = 0.f;
                if (1 * 16 + col > qloc) p1 = 0.f;
                if (2 * 16 + col > qloc) p2 = 0.f;
                if (3 * 16 + col > qloc) p3 = 0.f;
            }
            l_lane[r] += p0 + p1 + p2 + p3;
            Ps[w][quad * 4 + r][0 * 16 + col] = (__bf16)p0;
            Ps[w][quad * 4 + r][1 * 16 + col] = (__bf16)p1;
            Ps[w][quad * 4 + r][2 * 16 + col] = (__bf16)p2;
            Ps[w][quad * 4 + r][3 * 16 + col] = (__bf16)p3;
        }

        bf16x8 pf[2];
        #pragma unroll
        for (int ks = 0; ks < 2; ks++)
            pf[ks] = *reinterpret_cast<const bf16x8*>(&Ps[w][col][ks * 32 + quad * 8]);
        #pragma unroll
        for (int n = 0; n < 8; n++) {
            #pragma unroll
            for (int ks = 0; ks < 2; ks++) {
                bf16x8 vf = *reinterpret_cast<const bf16x8*>(
                    &Vt[n * 16 + col][ks * 32 + quad * 8]);
                o_acc[n] = __builtin_amdgcn_mfma_f32_16x16x32_bf16(pf[ks], vf, o_acc[n], 0, 0, 0);
            }
        }
    }

    #pragma unroll
    for (int r = 0; r < 4; r++) {
        float l = row_sum16(l_lane[r]);
        float inv = 1.0f / l;
        int qrow = r0 + w * 16 + quad * 4 + r;
        __bf16* op = ao + (size_t)(b * S_ + qrow) * (H_ * HD_) + h * HD_ + col;
        #pragma unroll
        for (int n = 0; n < 8; n++)
            op[n * 16] = (__bf16)(o_acc[n][r] * inv);
    }
}

// ---------------------------------------------------------------------------
extern "C" void kernel_launch(void* const* d_in, const int* in_sizes, int n_in,
                              void* d_out, int out_size, void* d_ws, size_t ws_size,
                              hipStream_t stream) {
    const float* x  = (const float*)d_in[0];
    const float* wq = (const float*)d_in[1];
    const float* wk = (const float*)d_in[2];
    const float* wv = (const float*)d_in[3];
    const float* wo = (const float*)d_in[4];
    const float* qw = (const float*)d_in[5];
    const float* kw = (const float*)d_in[6];
    float* out = (float*)d_out;

    // workspace (bf16 elements), total 50.33M elems = 100.66 MB
    __bf16* ws  = (__bf16*)d_ws;
    __bf16* xb  = ws;                               // [4096][2048]  8.4M
    __bf16* wb  = xb  + (size_t)8388608;            // [4096][2048]  8.4M (wq|wk|wv)
    __bf16* wob = wb  + (size_t)8388608;            // [2048][2048]  4.2M
    __bf16* qkv = wob + (size_t)4194304;            // [4096][4096] 16.8M
    __bf16* ao  = qkv + (size_t)16777216;           // [4096][2048]  8.4M
    __bf16* vtg = ao  + (size_t)8388608;            // [16][128][2048] 4.2M
    // rope table lives in the ao region (dead until attn writes it)
    float* rtab = (float*)ao;                       // [2048][128] fp32 = 1 MB

    cvt_all<<<20480, 256, 0, stream>>>(x, wq, wk, wv, wo, xb, wb, wob);
    build_rope<<<S_, 128, 0, stream>>>(rtab);

    // fused QKV projection: 256^2 8-phase (R4 schedule), 256 blocks (XCD swz)
    gemm_bf16_8ph<<<256, 512, 0, stream>>>(xb, wb, qkv, BS_, NQKV, D_);

    // RMSNorm + RoPE on q+k (24 heads x 4096 rows, 16 heads/block)
    norm_rope<<<(BS_ * 24) / 16, 256, 0, stream>>>(qkv, qw, kw, rtab);

    // global V^T
    transpose_v<<<dim3(S_ / 64, B_ * HK_), 256, 0, stream>>>(qkv, vtg);

    // causal GQA attention (R4 config: 64-row q-tiles, 1024 blocks, big-first)
    attn_mfma<<<dim3(B_ * H_, S_ / 64), 256, 0, stream>>>(qkv, vtg, ao);

    // output projection: 128x128 tiles -> 16x32 = 512 blocks (2/CU)
    gemm_bf16_nt<float><<<dim3(D_ / 128, BS_ / 128), 256, 0, stream>>>(
        ao, wob, out, BS_, D_, H_ * HD_);
}

// Round 11
// 325.422 us; speedup vs baseline: 1.0727x; 1.0071x over previous
//
#include <hip/hip_runtime.h>
#include <hip/hip_bf16.h>
#include <math.h>

// Problem constants (Qwen3-style attention block)
#define B_   2
#define S_   2048
#define D_   2048
#define H_   16
#define HK_  8
#define HD_  128
#define BS_  (B_ * S_)          // 4096 rows
#define NQKV 4096               // combined q(2048) + k(1024) + v(1024) cols
#define SCALE 0.08838834764831845f  // 1/sqrt(128)

typedef __bf16 bf16x8 __attribute__((ext_vector_type(8)));
typedef __bf16 bf16x4 __attribute__((ext_vector_type(4)));
typedef float  f32x4  __attribute__((ext_vector_type(4)));

#define AS1(p) ((const __attribute__((address_space(1))) void*)(p))
#define AS3(p) ((__attribute__((address_space(3))) void*)(p))

// 16-lane (DPP row) rotate-reduce sum: VALU latency, no LDS round-trip.
template <int S>
__device__ __forceinline__ float ror16(float x) {
    return __builtin_bit_cast(float, __builtin_amdgcn_update_dpp(
        0, __builtin_bit_cast(int, x), 0x120 | S, 0xF, 0xF, true));
}
__device__ __forceinline__ float row_sum16(float x) {
    x += ror16<8>(x);
    x += ror16<4>(x);
    x += ror16<2>(x);
    x += ror16<1>(x);
    return x;
}

// ---------------------------------------------------------------------------
// All fp32 -> bf16 converts + RoPE table build in ONE launch (R11 merge).
// Block ranges: x 8192, wq 4096, wk 2048, wv 2048, wo 4096, rope 1024
// -> 21504 blocks. Rope blocks: 2 s-rows each (256 thr, 128/row).
// ---------------------------------------------------------------------------
__global__ __launch_bounds__(256) void cvt_all(const float* __restrict__ x,
                                               const float* __restrict__ wq,
                                               const float* __restrict__ wk,
                                               const float* __restrict__ wv,
                                               const float* __restrict__ wo,
                                               __bf16* __restrict__ xb,
                                               __bf16* __restrict__ wb,
                                               __bf16* __restrict__ wob,
                                               float* __restrict__ rtab) {
    int bid = blockIdx.x;
    if (bid >= 20480) {
        // RoPE cos/sin table: tab[s][0..63]=cos, tab[s][64..127]=sin
        int idx = bid - 20480;                       // 0..1023
        int s = idx * 2 + (threadIdx.x >> 7);
        int d = threadIdx.x & 127;
        int i = d & 63;
        float inv_freq = exp2f(-19.931568569324174f * (float)(2 * i) * (1.0f / 128.0f));
        float ang = (float)s * inv_freq;
        float sn, cs;
        sincosf(ang, &sn, &cs);
        rtab[s * 128 + d] = (d < 64) ? cs : sn;
        return;
    }
    const float* src;
    __bf16* dst;
    int i4;
    if (bid < 8192)       { src = x;  dst = xb;                    i4 = bid * 256; }
    else if (bid < 12288) { src = wq; dst = wb;                    i4 = (bid - 8192) * 256; }
    else if (bid < 14336) { src = wk; dst = wb + (size_t)4194304;  i4 = (bid - 12288) * 256; }
    else if (bid < 16384) { src = wv; dst = wb + (size_t)6291456;  i4 = (bid - 14336) * 256; }
    else                  { src = wo; dst = wob;                   i4 = (bid - 16384) * 256; }
    i4 += threadIdx.x;
    float4 v = reinterpret_cast<const float4*>(src)[i4];
    bf16x4 o = {(__bf16)v.x, (__bf16)v.y, (__bf16)v.z, (__bf16)v.w};
    reinterpret_cast<bf16x4*>(dst)[i4] = o;
}

// ---------------------------------------------------------------------------
// 256x256 8-phase bf16 MFMA NT GEMM — R11: R4 schedule MINUS the manual
// lgkmcnt(0)+sched_barrier(0). Cycle audit (R10): per CU per K-tile,
// MFMA = 512x4.85 = 2483 cy vs LDS frag reads = 192x12 = 2304 cy — near
// equal. The explicit lgkm0 drain forced all 12 reads complete before ANY
// MFMA -> the two windows serialized (2483+2304 ~ measured 88 us, MfmaUtil
// 33%). Compiler auto-inserts COUNTED lgkmcnt before each dependent MFMA
// (m97 asm: lgkmcnt(4/3/1/0)) -> early fragments feed MFMA while later
// reads are serviced. Safety unchanged: every read consumed (completed)
// in its own phase; overwrites >=1 barrier later; raw s_barrier doesn't
// drain (same in-flight window R4 verified).
// ---------------------------------------------------------------------------
__global__ __launch_bounds__(512, 2) void gemm_bf16_8ph(const __bf16* __restrict__ A,
                                                        const __bf16* __restrict__ W,
                                                        __bf16* __restrict__ C,
                                                        int M, int N, int K) {
    __shared__ __bf16 lds[2][2][256 * 64];   // [buf][A=0/B=1][row*64 + chunk]

    const int t    = threadIdx.x;            // 0..511
    const int w    = t >> 6;                 // wave 0..7
    const int lane = t & 63;
    const int col  = lane & 15;
    const int quad = lane >> 4;
    const int c7   = col & 7;
    const int wm   = w >> 2;                 // 0..1  (2 M-warps, 128 rows each)
    const int wn   = w & 3;                  // 0..3  (4 N-warps, 64 cols each)

    // XCD-aware supertile swizzle (16x16 block grid, 8 XCDs, 256%8==0).
    const int bid = blockIdx.x;
    const int nid = (bid & 7) * 32 + (bid >> 3);
    const int st  = nid >> 4;
    const int wi  = nid & 15;
    const int m0 = ((st >> 2) * 4 + (wi >> 2)) * 256;
    const int n0 = ((st & 3) * 4 + (wi & 3)) * 256;

    // staging source (per-lane): wave w covers rows w*16..w*16+15 of a half
    const int lr8 = lane >> 3;                       // 0..7
    const int sw8 = ((lane & 7) ^ lr8) * 8;          // swizzled K-chunk (elems)
    const __bf16* Ag = A + (size_t)(m0 + w * 16 + lr8) * K + sw8;
    const __bf16* Wg = W + (size_t)(n0 + w * 16 + lr8) * K + sw8;

    const int nkt = K >> 6;      // number of 64-wide K-tiles (32 for K=2048)
    const int nit = nkt >> 1;    // main-loop iterations (2 K-tiles each)

    // fragment read bases (element offsets within a [256][64] panel)
    const int aBase = (wm * 128 + col) * 64;
    const int bBase = (wn * 64 + col) * 64;
    const int kx0 = (quad ^ c7) * 8;                 // kk=0 chunk offset
    const int kx1 = ((4 + quad) ^ c7) * 8;           // kk=1

    f32x4 acc[8][4];
    #pragma unroll
    for (int i = 0; i < 8; i++)
        #pragma unroll
        for (int j = 0; j < 4; j++) acc[i][j] = (f32x4){0.f, 0.f, 0.f, 0.f};

    bf16x8 a[4][2], a2[4][2], b0f[2][2], b1f[2][2];

    auto stg = [&](int ktv, int bufc, int ab, int half) {
        if (ktv >= nkt) return;
        const __bf16* gb = (ab ? Wg : Ag) + (size_t)half * 128 * K + (size_t)ktv * 64;
        __bf16* db = &lds[bufc][ab][(half * 128 + w * 16) * 64];
        __builtin_amdgcn_global_load_lds(AS1(gb), AS3(db), 16, 0, 0);
        __builtin_amdgcn_global_load_lds(AS1(gb + (size_t)8 * K), AS3(db + 512), 16, 0, 0);
    };
    auto lda = [&](bf16x8 (&dst)[4][2], const __bf16* panel, int g) {
        #pragma unroll
        for (int mi = 0; mi < 4; mi++) {
            dst[mi][0] = *reinterpret_cast<const bf16x8*>(&panel[aBase + (g * 64 + mi * 16) * 64 + kx0]);
            dst[mi][1] = *reinterpret_cast<const bf16x8*>(&panel[aBase + (g * 64 + mi * 16) * 64 + kx1]);
        }
    };
    auto ldb = [&](bf16x8 (&dst)[2][2], const __bf16* panel, int ng) {
        #pragma unroll
        for (int ni = 0; ni < 2; ni++) {
            dst[ni][0] = *reinterpret_cast<const bf16x8*>(&panel[bBase + (ng * 32 + ni * 16) * 64 + kx0]);
            dst[ni][1] = *reinterpret_cast<const bf16x8*>(&panel[bBase + (ng * 32 + ni * 16) * 64 + kx1]);
        }
    };
    auto mm = [&](bf16x8 (&af)[4][2], bf16x8 (&bfr)[2][2], int g, int ng) {
        __builtin_amdgcn_s_setprio(1);
        #pragma unroll
        for (int mi = 0; mi < 4; mi++)
            #pragma unroll
            for (int ni = 0; ni < 2; ni++) {
                f32x4 c = acc[g * 4 + mi][ng * 2 + ni];
                c = __builtin_amdgcn_mfma_f32_16x16x32_bf16(af[mi][0], bfr[ni][0], c, 0, 0, 0);
                c = __builtin_amdgcn_mfma_f32_16x16x32_bf16(af[mi][1], bfr[ni][1], c, 0, 0, 0);
                acc[g * 4 + mi][ng * 2 + ni] = c;
            }
        __builtin_amdgcn_s_setprio(0);
    };

#define BAR  __builtin_amdgcn_s_barrier()
#define VM(n) asm volatile("s_waitcnt vmcnt(" #n ")" ::: "memory")

    // ---- prologue: kt0 {A0,A1,B0,B1}, kt1 {A0,A1}; land kt0, keep 2 in flight
    stg(0, 0, 0, 0); stg(0, 0, 0, 1); stg(0, 0, 1, 0); stg(0, 0, 1, 1);
    stg(1, 1, 0, 0); stg(1, 1, 0, 1);
    VM(4);
    BAR;

    #pragma unroll 1
    for (int it = 0; it < nit; ++it) {
        const int k2 = it * 2;
        const bool last = (it == nit - 1);

        const __bf16* A0p = &lds[0][0][0];
        const __bf16* B0p = &lds[0][1][0];
        const __bf16* A1p = &lds[1][0][0];
        const __bf16* B1p = &lds[1][1][0];

        // ---- K-tile k2 (buf0): phases 1-4
        lda(a, A0p, 0); ldb(b0f, B0p, 0);
        stg(k2 + 1, 1, 1, 0);
        BAR;
        mm(a, b0f, 0, 0);
        lda(a2, A0p, 1);
        stg(k2 + 1, 1, 1, 1);
        BAR;
        mm(a2, b0f, 1, 0);
        ldb(b1f, B0p, 1);
        stg(k2 + 2, 0, 0, 0);
        BAR;
        mm(a, b1f, 0, 1);
        stg(k2 + 2, 0, 0, 1);
        if (last) VM(0); else VM(4);
        BAR;
        mm(a2, b1f, 1, 1);

        // ---- K-tile k2+1 (buf1): phases 5-8
        lda(a, A1p, 0); ldb(b0f, B1p, 0);
        stg(k2 + 2, 0, 1, 0);
        BAR;
        mm(a, b0f, 0, 0);
        lda(a2, A1p, 1);
        stg(k2 + 2, 0, 1, 1);
        BAR;
        mm(a2, b0f, 1, 0);
        ldb(b1f, B1p, 1);
        stg(k2 + 3, 1, 0, 0);
        BAR;
        mm(a, b1f, 0, 1);
        stg(k2 + 3, 1, 0, 1);
        if (!last) { VM(4); }
        BAR;
        mm(a2, b1f, 1, 1);
    }

#undef BAR
#undef VM

    // ---- epilogue: C write (verified C/D mapping)
    #pragma unroll
    for (int m8 = 0; m8 < 8; m8++) {
        #pragma unroll
        for (int r = 0; r < 4; r++) {
            size_t row = m0 + wm * 128 + m8 * 16 + quad * 4 + r;
            __bf16* cp = C + row * N + n0 + wn * 64 + col;
            #pragma unroll
            for (int n4 = 0; n4 < 4; n4++) cp[n4 * 16] = (__bf16)acc[m8][n4][r];
        }
    }
}

// ---------------------------------------------------------------------------
// bf16 MFMA NT GEMM: C[M,N] = A[M,K] * W[N,K]^T
// 128x128 tile, BK=64, 256 threads = 4 waves (2x2). Out-proj: N=2048 ->
// grid 16x32 = 512 blocks (2/CU co-resident).
// ---------------------------------------------------------------------------
template <typename CT>
__global__ __launch_bounds__(256) void gemm_bf16_nt(const __bf16* __restrict__ A,
                                                    const __bf16* __restrict__ W,
                                                    CT* __restrict__ C,
                                                    int M, int N, int K) {
    __shared__ __bf16 As[128 * 64];
    __shared__ __bf16 Bs[128 * 64];

    const int t    = threadIdx.x;
    const int w    = t >> 6;
    const int lane = t & 63;
    const int col  = lane & 15;
    const int quad = lane >> 4;
    const int wm   = w >> 1;
    const int wn   = w & 1;

    const int m0 = blockIdx.y * 128;
    const int n0 = blockIdx.x * 128;

    const int lrow8 = lane >> 3;                     // 0..7
    const int lch   = ((lane & 7) ^ lrow8) * 8;      // swizzled K-chunk

    const __bf16* agp = A + (size_t)(m0 + w * 32 + lrow8) * K + lch;
    const __bf16* wgp = W + (size_t)(n0 + w * 32 + lrow8) * K + lch;
    __bf16* alp = As + (w * 32) * 64;
    __bf16* blp = Bs + (w * 32) * 64;

    const int c7 = col & 7;

    f32x4 acc[4][4];
    #pragma unroll
    for (int m = 0; m < 4; m++)
        #pragma unroll
        for (int n = 0; n < 4; n++) acc[m][n] = (f32x4){0.f, 0.f, 0.f, 0.f};

    #pragma unroll 1
    for (int k0 = 0; k0 < K; k0 += 64) {
        #pragma unroll
        for (int j = 0; j < 4; j++) {
            __builtin_amdgcn_global_load_lds(AS1(agp + k0 + (size_t)(j * 8) * K),
                                             AS3(alp + j * 512), 16, 0, 0);
            __builtin_amdgcn_global_load_lds(AS1(wgp + k0 + (size_t)(j * 8) * K),
                                             AS3(blp + j * 512), 16, 0, 0);
        }
        __syncthreads();

        #pragma unroll
        for (int kk = 0; kk < 2; kk++) {
            bf16x8 af[4], bfr[4];
            #pragma unroll
            for (int m = 0; m < 4; m++)
                af[m] = *reinterpret_cast<const bf16x8*>(
                    &As[(wm * 64 + m * 16 + col) * 64 + ((kk * 4 + quad) ^ c7) * 8]);
            #pragma unroll
            for (int n = 0; n < 4; n++)
                bfr[n] = *reinterpret_cast<const bf16x8*>(
                    &Bs[(wn * 64 + n * 16 + col) * 64 + ((kk * 4 + quad) ^ c7) * 8]);

            #pragma unroll
            for (int m = 0; m < 4; m++)
                #pragma unroll
                for (int n = 0; n < 4; n++)
                    acc[m][n] = __builtin_amdgcn_mfma_f32_16x16x32_bf16(af[m], bfr[n], acc[m][n], 0, 0, 0);
        }
        __syncthreads();
    }

    #pragma unroll
    for (int m = 0; m < 4; m++) {
        #pragma unroll
        for (int r = 0; r < 4; r++) {
            size_t row = m0 + wm * 64 + m * 16 + quad * 4 + r;
            CT* cp = C + row * N + n0 + wn * 64 + col;
            #pragma unroll
            for (int n = 0; n < 4; n++) cp[n * 16] = (CT)acc[m][n][r];
        }
    }
}

// ---------------------------------------------------------------------------
// Fused per-head RMSNorm + RoPE  +  V transpose (R11 merge: disjoint qkv
// columns — norm touches cols <3072, transpose reads cols >=3072).
// Blocks 0..6143: norm_rope (16 head-instances each).
// Blocks 6144..6655: transpose_v (512 blocks: idx&31 = s-tile, idx>>5 = bk).
// ---------------------------------------------------------------------------
__global__ __launch_bounds__(256) void norm_rope_tv(__bf16* __restrict__ qkv,
                                                    const float* __restrict__ qw,
                                                    const float* __restrict__ kw,
                                                    const float* __restrict__ tab,
                                                    __bf16* __restrict__ vt) {
    if (blockIdx.x >= 6144) {
        // ---- V transpose: vt[(b*HK+kvh)*128 + dim][s] = v[b*S+s][kvh*128+dim]
        __shared__ __bf16 Ls[64][136];
        const int t  = threadIdx.x;
        const int idx = blockIdx.x - 6144;    // 0..511
        const int bk = idx >> 5;              // b*8 + kvh
        const int b  = bk >> 3;
        const int kvh = bk & 7;
        const int s0 = (idx & 31) * 64;

        #pragma unroll
        for (int i = 0; i < 4; i++) {
            int f = t + i * 256;
            int row = f >> 4;
            int d8 = (f & 15) * 8;
            bf16x8 v = *reinterpret_cast<const bf16x8*>(
                &qkv[(size_t)(b * S_ + s0 + row) * NQKV + 3072 + kvh * HD_ + d8]);
            *reinterpret_cast<bf16x8*>(&Ls[row][d8]) = v;
        }
        __syncthreads();

        #pragma unroll
        for (int i = 0; i < 4; i++) {
            int f = t + i * 256;
            int dim = f >> 3;
            int kc = f & 7;
            bf16x8 o;
            #pragma unroll
            for (int e = 0; e < 8; e++) o[e] = Ls[kc * 8 + e][dim];
            *reinterpret_cast<bf16x8*>(
                &vt[((size_t)bk * HD_ + dim) * S_ + s0 + kc * 8]) = o;
        }
        return;
    }

    // ---- norm_rope: one head per 16-lane DPP row, 16 heads/block.
    const int g    = blockIdx.x * 16 + (threadIdx.x >> 4);  // head-instance
    const int l    = threadIdx.x & 15;
    const int row  = g / 24;
    const int head = g - row * 24;
    const int s    = row & (S_ - 1);

    const float* w = (head < H_) ? qw : kw;
    __bf16* p = qkv + (size_t)row * NQKV + head * HD_ + l * 8;

    bf16x8 xv = *reinterpret_cast<const bf16x8*>(p);
    float xf[8];
    float ss = 0.f;
    #pragma unroll
    for (int j = 0; j < 8; j++) { xf[j] = (float)xv[j]; ss = fmaf(xf[j], xf[j], ss); }
    ss = row_sum16(ss);
    float rs = rsqrtf(ss * (1.0f / 128.0f) + 1e-6f);

    // normed value (fp32)
    float nf[8];
    const float4 w0 = *reinterpret_cast<const float4*>(&w[l * 8]);
    const float4 w1 = *reinterpret_cast<const float4*>(&w[l * 8 + 4]);
    nf[0] = xf[0] * rs * w0.x; nf[1] = xf[1] * rs * w0.y;
    nf[2] = xf[2] * rs * w0.z; nf[3] = xf[3] * rs * w0.w;
    nf[4] = xf[4] * rs * w1.x; nf[5] = xf[5] * rs * w1.y;
    nf[6] = xf[6] * rs * w1.z; nf[7] = xf[7] * rs * w1.w;

    // RoPE pair values from the other half (lane l^8, same j)
    float of[8];
    #pragma unroll
    for (int j = 0; j < 8; j++) of[j] = __shfl_xor(nf[j], 8);

    // cos/sin for freq index i = (l&7)*8 + j
    const int ib = (l & 7) * 8;
    const float4 c0 = *reinterpret_cast<const float4*>(&tab[s * 128 + ib]);
    const float4 c1 = *reinterpret_cast<const float4*>(&tab[s * 128 + ib + 4]);
    const float4 s0 = *reinterpret_cast<const float4*>(&tab[s * 128 + 64 + ib]);
    const float4 s1 = *reinterpret_cast<const float4*>(&tab[s * 128 + 64 + ib + 4]);
    float cs[8] = {c0.x, c0.y, c0.z, c0.w, c1.x, c1.y, c1.z, c1.w};
    float sn[8] = {s0.x, s0.y, s0.z, s0.w, s1.x, s1.y, s1.z, s1.w};

    bf16x8 out;
    if (l < 8) {
        #pragma unroll
        for (int j = 0; j < 8; j++) out[j] = (__bf16)(nf[j] * cs[j] - of[j] * sn[j]);
    } else {
        #pragma unroll
        for (int j = 0; j < 8; j++) out[j] = (__bf16)(of[j] * sn[j] + nf[j] * cs[j]);
    }
    *reinterpret_cast<bf16x8*>(p) = out;
}

// ---------------------------------------------------------------------------
// MFMA bf16 flash attention (causal, GQA rep=2), fixed-max softmax.
// R4's exact kernel (best measured config): QBLK=64, 4 waves, 1024 blocks,
// 3 blocks/CU (LDS 45056 B), big q-tiles dispatched first.
// ---------------------------------------------------------------------------
__global__ __launch_bounds__(256) void attn_mfma(const __bf16* __restrict__ qkv,
                                                 const __bf16* __restrict__ vt,
                                                 __bf16* __restrict__ ao) {
    __shared__ __align__(16) char smem[17408];
    __bf16 (*Qs)[136] = reinterpret_cast<__bf16(*)[136]>(smem);
    __bf16 (*Ks)[136] = reinterpret_cast<__bf16(*)[136]>(smem);
    __shared__ __bf16 Vt[128][72];
    __shared__ __bf16 Ps[4][16][72];

    const int t    = threadIdx.x;
    const int w    = t >> 6;
    const int lane = t & 63;
    const int col  = lane & 15;
    const int quad = lane >> 4;

    const int bh  = blockIdx.x;
    const int b   = bh >> 4;
    const int h   = bh & 15;
    const int kvh = h >> 1;
    const int qb  = gridDim.y - 1 - blockIdx.y;   // big q-tiles first
    const int r0  = qb * 64;

    const float C0 = SCALE * 1.44269504f;
    const float CM = -12.0f * 1.44269504f;

    const __bf16* vbase = vt + ((size_t)(b * HK_ + kvh) * HD_) * S_;

    const __bf16* kp[4];
    __bf16*       kw_[4];
    const __bf16* vp[4];
    __bf16*       vw_[4];
    #pragma unroll
    for (int i = 0; i < 4; i++) {
        int f = t + i * 256;
        int row = f >> 4, d8 = (f & 15) * 8;
        kp[i]  = qkv + (size_t)(b * S_ + row) * NQKV + 2048 + kvh * HD_ + d8;
        kw_[i] = &Ks[row][d8];
        int dim = f >> 3, kc = f & 7;
        vp[i]  = vbase + (size_t)dim * S_ + kc * 8;
        vw_[i] = &Vt[dim][kc * 8];
    }

    bf16x8 kreg[4], vreg[4];
    #pragma unroll
    for (int i = 0; i < 4; i++) {
        kreg[i] = *reinterpret_cast<const bf16x8*>(kp[i]);  kp[i] += (size_t)64 * NQKV;
        vreg[i] = *reinterpret_cast<const bf16x8*>(vp[i]);  vp[i] += 64;
    }

    #pragma unroll
    for (int i = 0; i < 4; i++) {
        int f   = t + i * 256;
        int row = f >> 4;
        int d8  = (f & 15) * 8;
        bf16x8 v = *reinterpret_cast<const bf16x8*>(
            &qkv[(size_t)(b * S_ + r0 + row) * NQKV + h * HD_ + d8]);
        *reinterpret_cast<bf16x8*>(&Qs[row][d8]) = v;
    }
    __syncthreads();

    bf16x8 qf[4];
    {
        const int m = w * 16 + col;
        #pragma unroll
        for (int k = 0; k < 4; k++)
            qf[k] = *reinterpret_cast<const bf16x8*>(&Qs[m][k * 32 + quad * 8]);
    }

    f32x4 o_acc[8];
    #pragma unroll
    for (int i = 0; i < 8; i++) o_acc[i] = (f32x4){0.f, 0.f, 0.f, 0.f};
    float l_lane[4] = {0.f, 0.f, 0.f, 0.f};

    const int ntiles = qb + 1;
    for (int ti = 0; ti < ntiles; ti++) {
        __syncthreads();

        #pragma unroll
        for (int i = 0; i < 4; i++) {
            *reinterpret_cast<bf16x8*>(kw_[i]) = kreg[i];
            *reinterpret_cast<bf16x8*>(vw_[i]) = vreg[i];
        }
        if (ti + 1 < ntiles) {
            #pragma unroll
            for (int i = 0; i < 4; i++) {
                kreg[i] = *reinterpret_cast<const bf16x8*>(kp[i]);  kp[i] += (size_t)64 * NQKV;
                vreg[i] = *reinterpret_cast<const bf16x8*>(vp[i]);  vp[i] += 64;
            }
        }
        __syncthreads();

        f32x4 s[4];
        #pragma unroll
        for (int n = 0; n < 4; n++) {
            f32x4 acc = (f32x4){0.f, 0.f, 0.f, 0.f};
            #pragma unroll
            for (int k = 0; k < 4; k++) {
                bf16x8 bf = *reinterpret_cast<const bf16x8*>(
                    &Ks[n * 16 + col][k * 32 + quad * 8]);
                acc = __builtin_amdgcn_mfma_f32_16x16x32_bf16(qf[k], bf, acc, 0, 0, 0);
            }
            s[n] = acc;
        }

        const bool diag = (ti == qb);
        #pragma unroll
        for (int r = 0; r < 4; r++) {
            float p0 = exp2f(fmaf(s[0][r], C0, CM));
            float p1 = exp2f(fmaf(s[1][r], C0, CM));
            float p2 = exp2f(fmaf(s[2][r], C0, CM));
            float p3 = exp2f(fmaf(s[3][r], C0, CM));
            if (diag) {
                int qloc = w * 16 + quad * 4 + r;
                if (0 * 16 + col > qloc) p0 = 0.f;
                if (1 * 16 + col > qloc) p1 = 0.f;
                if (2 * 16 + col > qloc) p2 = 0.f;
                if (3 * 16 + col > qloc) p3 = 0.f;
            }
            l_lane[r] += p0 + p1 + p2 + p3;
            Ps[w][quad * 4 + r][0 * 16 + col] = (__bf16)p0;
            Ps[w][quad * 4 + r][1 * 16 + col] = (__bf16)p1;
            Ps[w][quad * 4 + r][2 * 16 + col] = (__bf16)p2;
            Ps[w][quad * 4 + r][3 * 16 + col] = (__bf16)p3;
        }

        bf16x8 pf[2];
        #pragma unroll
        for (int ks = 0; ks < 2; ks++)
            pf[ks] = *reinterpret_cast<const bf16x8*>(&Ps[w][col][ks * 32 + quad * 8]);
        #pragma unroll
        for (int n = 0; n < 8; n++) {
            #pragma unroll
            for (int ks = 0; ks < 2; ks++) {
                bf16x8 vf = *reinterpret_cast<const bf16x8*>(
                    &Vt[n * 16 + col][ks * 32 + quad * 8]);
                o_acc[n] = __builtin_amdgcn_mfma_f32_16x16x32_bf16(pf[ks], vf, o_acc[n], 0, 0, 0);
            }
        }
    }

    #pragma unroll
    for (int r = 0; r < 4; r++) {
        float l = row_sum16(l_lane[r]);
        float inv = 1.0f / l;
        int qrow = r0 + w * 16 + quad * 4 + r;
        __bf16* op = ao + (size_t)(b * S_ + qrow) * (H_ * HD_) + h * HD_ + col;
        #pragma unroll
        for (int n = 0; n < 8; n++)
            op[n * 16] = (__bf16)(o_acc[n][r] * inv);
    }
}

// ---------------------------------------------------------------------------
extern "C" void kernel_launch(void* const* d_in, const int* in_sizes, int n_in,
                              void* d_out, int out_size, void* d_ws, size_t ws_size,
                              hipStream_t stream) {
    const float* x  = (const float*)d_in[0];
    const float* wq = (const float*)d_in[1];
    const float* wk = (const float*)d_in[2];
    const float* wv = (const float*)d_in[3];
    const float* wo = (const float*)d_in[4];
    const float* qw = (const float*)d_in[5];
    const float* kw = (const float*)d_in[6];
    float* out = (float*)d_out;

    // workspace (bf16 elements), total 50.33M elems = 100.66 MB
    __bf16* ws  = (__bf16*)d_ws;
    __bf16* xb  = ws;                               // [4096][2048]  8.4M
    __bf16* wb  = xb  + (size_t)8388608;            // [4096][2048]  8.4M (wq|wk|wv)
    __bf16* wob = wb  + (size_t)8388608;            // [2048][2048]  4.2M
    __bf16* qkv = wob + (size_t)4194304;            // [4096][4096] 16.8M
    __bf16* ao  = qkv + (size_t)16777216;           // [4096][2048]  8.4M
    __bf16* vtg = ao  + (size_t)8388608;            // [16][128][2048] 4.2M
    // rope table lives in the ao region (dead until attn writes it)
    float* rtab = (float*)ao;                       // [2048][128] fp32 = 1 MB

    // converts + rope table in one launch
    cvt_all<<<21504, 256, 0, stream>>>(x, wq, wk, wv, wo, xb, wb, wob, rtab);

    // fused QKV projection: 256^2 8-phase (R11: no manual lgkm drain)
    gemm_bf16_8ph<<<256, 512, 0, stream>>>(xb, wb, qkv, BS_, NQKV, D_);

    // RMSNorm + RoPE on q+k  +  V transpose (merged)
    norm_rope_tv<<<6656, 256, 0, stream>>>(qkv, qw, kw, rtab, vtg);

    // causal GQA attention (R4 config: 64-row q-tiles, 1024 blocks, big-first)
    attn_mfma<<<dim3(B_ * H_, S_ / 64), 256, 0, stream>>>(qkv, vtg, ao);

    // output projection: 128x128 tiles -> 16x32 = 512 blocks (2/CU)
    gemm_bf16_nt<float><<<dim3(D_ / 128, BS_ / 128), 256, 0, stream>>>(
        ao, wob, out, BS_, D_, H_ * HD_);
}